// Round 5
// baseline (209.794 us; speedup 1.0000x reference)
//
#include <hip/hip_runtime.h>
#include <math.h>

// Problem constants (fixed by setup_inputs)
#define BB 256      // batch
#define TT 256      // time steps
#define NQ 1000     // num_q
#define DK 128
#define DV 128
#define CC 32

typedef short s16x8 __attribute__((ext_vector_type(8)));   // 8 bf16 bit-patterns
typedef float f32x4 __attribute__((ext_vector_type(4)));
typedef float f32x2 __attribute__((ext_vector_type(2)));
typedef float f32x16 __attribute__((ext_vector_type(16)));

__device__ __forceinline__ float fast_sigmoid(float x) {
    x = fminf(fmaxf(x, -30.f), 30.f);
    return 1.f / (1.f + __expf(-x));
}
__device__ __forceinline__ float fast_tanh(float x) {
    x = fminf(fmaxf(x, -15.f), 15.f);
    float t = __expf(2.f * x);
    return (t - 1.f) / (t + 1.f);
}
__device__ __forceinline__ unsigned short f2bf(float f) {   // RNE fp32->bf16
    unsigned u = __float_as_uint(f);
    u += 0x7fffu + ((u >> 16) & 1u);
    return (unsigned short)(u >> 16);
}
__device__ __forceinline__ float bf2f(unsigned short h) {
    return __uint_as_float((unsigned)h << 16);
}
__device__ __forceinline__ unsigned u4get(uint4 v, int i) { // i constant after unroll
    return i == 0 ? v.x : i == 1 ? v.y : i == 2 ? v.z : v.w;
}
__device__ __forceinline__ f32x2 mk2(float x, float y) { f32x2 r; r.x = x; r.y = y; return r; }
__device__ __forceinline__ f32x2 fma2(f32x2 a, f32x2 b, f32x2 c) {
    return __builtin_elementwise_fma(a, b, c);
}
__device__ __forceinline__ s16x8 cvt8(float4 v0, float4 v1) {
    s16x8 f;
    f[0] = (short)f2bf(v0.x); f[1] = (short)f2bf(v0.y);
    f[2] = (short)f2bf(v0.z); f[3] = (short)f2bf(v0.w);
    f[4] = (short)f2bf(v1.x); f[5] = (short)f2bf(v1.y);
    f[6] = (short)f2bf(v1.z); f[7] = (short)f2bf(v1.w);
    return f;
}

// ---------------------------------------------------------------------------
// conv_kernel: build bf16 TRANSPOSED weights in ws (B-operand layout Wt[n][k])
// ---------------------------------------------------------------------------
__global__ __launch_bounds__(256) void conv_kernel(
    const float* __restrict__ eW, const float* __restrict__ aW,
    const float* __restrict__ fW, const float* __restrict__ Mk,
    unsigned short* __restrict__ eWt, unsigned short* __restrict__ aWt,
    unsigned short* __restrict__ fWat, unsigned short* __restrict__ fWbt,
    unsigned short* __restrict__ Mkt)
{
    int idx = blockIdx.x * 256 + threadIdx.x;
    if (idx < 16384) {
        int n = idx >> 7, k = idx & 127;
        eWt[idx] = f2bf(eW[k * 128 + n]);
    } else if (idx < 32768) {
        int i = idx - 16384; int n = i >> 7, k = i & 127;
        aWt[i] = f2bf(aW[k * 128 + n]);
    } else if (idx < 49152) {
        int i = idx - 32768; int n = i >> 7, k = i & 127;
        fWat[i] = f2bf(fW[k * 128 + n]);
    } else if (idx < 65536) {
        int i = idx - 49152; int n = i >> 7, k = i & 127;
        fWbt[i] = f2bf(fW[(128 + k) * 128 + n]);
    } else if (idx < 69632) {
        int i = idx - 65536; int n = i >> 7, k = i & 127;   // n=c 0..31
        Mkt[i] = f2bf(Mk[k * 32 + n]);
    }
}

// ---------------------------------------------------------------------------
// pre_kernel v2 (R11): same math, data movement minimized.
// ---------------------------------------------------------------------------
__global__ __launch_bounds__(256) void pre_kernel(
    const int* __restrict__ skills, const int* __restrict__ responses,
    const float* __restrict__ k_emb, const float* __restrict__ v_emb,
    const float* __restrict__ fb, const float* __restrict__ eb,
    const float* __restrict__ ab,
    const unsigned short* __restrict__ Mkt, const unsigned short* __restrict__ fWbt,
    const unsigned short* __restrict__ eWt, const unsigned short* __restrict__ aWt,
    float* __restrict__ Wo, unsigned* __restrict__ EA,
    unsigned short* __restrict__ Ko, float* __restrict__ outTrue,
    int t0, int Tc)
{
    const int tid = threadIdx.x;
    const int lane = tid & 63;
    const int m_base = (tid >> 6) * 16;
    const int mrow = lane & 15, quad = lane >> 4;
    const size_t base = (size_t)blockIdx.x * 64;

    __shared__ __align__(16) unsigned short Wlds[128 * 136];   // 34.8 KB

    // per-lane gather row (A-side): row = base + m_base + mrow
    int grow = (int)base + m_base + mrow;
    int gb = grow / Tc;
    int gt = t0 + (grow - gb * Tc);
    int gi = gb * TT + gt;
    int s = skills[gi];
    int r = responses[gi];
    int q = s + NQ * ((r > -1) ? r : 0);
    if (quad == 0 && gt >= 1) outTrue[gb * (TT - 1) + (gt - 1)] = (float)r;

    // stage Mkt rows 0..31
    {
        int n = tid >> 3, k0 = (tid & 7) * 16;
        *(s16x8*)&Wlds[n * 136 + k0]     = *(const s16x8*)&Mkt[n * 128 + k0];
        *(s16x8*)&Wlds[n * 136 + k0 + 8] = *(const s16x8*)&Mkt[n * 128 + k0 + 8];
    }

    // gather kt A-frags direct to regs: aF[kb] = kt[row][kb*32 + quad*8 ..+7]
    s16x8 aF[4];
    {
        const float* kr = k_emb + (size_t)s * DK + quad * 8;
#pragma unroll
        for (int kb = 0; kb < 4; ++kb)
            aF[kb] = cvt8(*(const float4*)(kr + kb * 32),
                          *(const float4*)(kr + kb * 32 + 4));
    }
    __syncthreads();   // [1] Mkt staged

    // logits (NT=2) + in-register softmax -> Wo
    {
        f32x4 l0 = {0.f, 0.f, 0.f, 0.f}, l1 = {0.f, 0.f, 0.f, 0.f};
#pragma unroll
        for (int kb = 0; kb < 4; ++kb) {
            s16x8 b0 = *(const s16x8*)&Wlds[mrow * 136 + kb * 32 + quad * 8];
            s16x8 b1 = *(const s16x8*)&Wlds[(16 + mrow) * 136 + kb * 32 + quad * 8];
            l0 = __builtin_amdgcn_mfma_f32_16x16x32_bf16(aF[kb], b0, l0, 0, 0, 0);
            l1 = __builtin_amdgcn_mfma_f32_16x16x32_bf16(aF[kb], b1, l1, 0, 0, 0);
        }
        // lane holds cols {mrow, 16+mrow} for rows m_base + quad*4 + reg
#pragma unroll
        for (int reg = 0; reg < 4; ++reg) {
            float a0 = l0[reg], a1 = l1[reg];
            float m = fmaxf(a0, a1);
#pragma unroll
            for (int off = 1; off < 16; off <<= 1)
                m = fmaxf(m, __shfl_xor(m, off, 64));
            float e0 = __expf(a0 - m), e1 = __expf(a1 - m);
            float ssum = e0 + e1;
#pragma unroll
            for (int off = 1; off < 16; off <<= 1)
                ssum += __shfl_xor(ssum, off, 64);
            float inv = 1.f / ssum;
            size_t rowg = base + m_base + quad * 4 + reg;
            Wo[rowg * 32 + mrow]      = e0 * inv;
            Wo[rowg * 32 + 16 + mrow] = e1 * inv;
        }
    }
    __syncthreads();   // [2] logits' Wlds reads done

    // stage fWbt
    {
        int n = tid >> 1, k0 = (tid & 1) * 64;
#pragma unroll
        for (int j = 0; j < 8; ++j)
            *(s16x8*)&Wlds[n * 136 + k0 + j * 8] = *(const s16x8*)&fWbt[n * 128 + k0 + j * 8];
    }
    __syncthreads();   // [3]

    // gather vt frags early (global latency overlaps ck MFMA below)
    s16x8 vF[4];
    {
        const float* vr = v_emb + (size_t)q * DV + quad * 8;
#pragma unroll
        for (int kb = 0; kb < 4; ++kb)
            vF[kb] = cvt8(*(const float4*)(vr + kb * 32),
                          *(const float4*)(vr + kb * 32 + 4));
    }

    // ck = kt@fWb + fb -> Ko
#pragma unroll
    for (int nt = 0; nt < 8; ++nt) {
        f32x4 acc = {0.f, 0.f, 0.f, 0.f};
#pragma unroll
        for (int kb = 0; kb < 4; ++kb) {
            s16x8 bf = *(const s16x8*)&Wlds[(nt * 16 + mrow) * 136 + kb * 32 + quad * 8];
            acc = __builtin_amdgcn_mfma_f32_16x16x32_bf16(aF[kb], bf, acc, 0, 0, 0);
        }
        int col = nt * 16 + mrow;
        float fbv = fb[col];
#pragma unroll
        for (int reg = 0; reg < 4; ++reg) {
            size_t rr = base + m_base + quad * 4 + reg;
            Ko[rr * 128 + col] = f2bf(acc[reg] + fbv);
        }
    }
    __syncthreads();   // [4] ck's Wlds reads done

    // stage eWt
    {
        int n = tid >> 1, k0 = (tid & 1) * 64;
#pragma unroll
        for (int j = 0; j < 8; ++j)
            *(s16x8*)&Wlds[n * 136 + k0 + j * 8] = *(const s16x8*)&eWt[n * 128 + k0 + j * 8];
    }
    __syncthreads();   // [5]

    // et = sigmoid(vt@eW + eb) -> registers
    float etr[8][4];
#pragma unroll
    for (int nt = 0; nt < 8; ++nt) {
        f32x4 acc = {0.f, 0.f, 0.f, 0.f};
#pragma unroll
        for (int kb = 0; kb < 4; ++kb) {
            s16x8 bf = *(const s16x8*)&Wlds[(nt * 16 + mrow) * 136 + kb * 32 + quad * 8];
            acc = __builtin_amdgcn_mfma_f32_16x16x32_bf16(vF[kb], bf, acc, 0, 0, 0);
        }
        int col = nt * 16 + mrow;
        float ebv = eb[col];
#pragma unroll
        for (int reg = 0; reg < 4; ++reg)
            etr[nt][reg] = fast_sigmoid(acc[reg] + ebv);
    }
    __syncthreads();   // [6] et's Wlds reads done

    // stage aWt
    {
        int n = tid >> 1, k0 = (tid & 1) * 64;
#pragma unroll
        for (int j = 0; j < 8; ++j)
            *(s16x8*)&Wlds[n * 136 + k0 + j * 8] = *(const s16x8*)&aWt[n * 128 + k0 + j * 8];
    }
    __syncthreads();   // [7]

    // at = tanh(vt@aW + ab); pack (et,at) -> EA
#pragma unroll
    for (int nt = 0; nt < 8; ++nt) {
        f32x4 acc = {0.f, 0.f, 0.f, 0.f};
#pragma unroll
        for (int kb = 0; kb < 4; ++kb) {
            s16x8 bf = *(const s16x8*)&Wlds[(nt * 16 + mrow) * 136 + kb * 32 + quad * 8];
            acc = __builtin_amdgcn_mfma_f32_16x16x32_bf16(vF[kb], bf, acc, 0, 0, 0);
        }
        int col = nt * 16 + mrow;
        float abv = ab[col];
#pragma unroll
        for (int reg = 0; reg < 4; ++reg) {
            size_t rr = base + m_base + quad * 4 + reg;
            int bb = (int)(rr / (size_t)Tc);
            int t  = (int)(rr - (size_t)bb * Tc);
            size_t o4 = (((size_t)bb * (Tc >> 5) + (t >> 5)) * 8 + ((t >> 2) & 7)) * 128 + col;
            unsigned lo = f2bf(etr[nt][reg]);
            unsigned hi = (unsigned)f2bf(fast_tanh(acc[reg] + abv)) << 16;
            EA[o4 * 4 + (t & 3)] = hi | lo;
        }
    }
}

// ---------------------------------------------------------------------------
// fused_kernel v9 (seq + post) — R15:
//  R14 + the structural fix for the 4x "illegal VGPR to SGPR copy": the
//  producer/consumer split now branches on a readfirstlane-uniformized
//  predicate, so the branch is compiler-visibly UNIFORM (s_cbranch, no
//  exec-mask divergence). The f32x16 SGPR w-buffers' loop PHIs are then
//  uniform -> legal SGPR allocation. (R14's failure: divergent tid<128
//  branch made the loop-carried PHIs on wA*/wB* divergent -> VGPR.)
//  Also: keep-alive asm takes the float4 component-wise ('v' can't take
//  128-bit aggregates).
// ---------------------------------------------------------------------------

#define CH 32
#define RSTR 136    // rtl/fWl row stride (shorts)

#define LOAD_EA(ER, gg) do {                                                  \
    const uint4* src = EA4 + ((size_t)(bq + (gg))) * 1024 + tid;              \
    _Pragma("unroll")                                                         \
    for (int j = 0; j < 8; ++j) ER[j] = src[j * 128];                         \
} while (0)

// issue the 32-float w row for global step gs into SGPR tuple pair (B0,B1).
#define WLOAD(B0, B1, gs) do {                                                \
    unsigned long long _up = (unsigned long long)(Wb + (size_t)(gs) * 32);    \
    unsigned _lo = __builtin_amdgcn_readfirstlane((unsigned)_up);             \
    unsigned _hi = __builtin_amdgcn_readfirstlane((unsigned)(_up >> 32));     \
    unsigned long long _sp = ((unsigned long long)_hi << 32) | _lo;           \
    asm volatile("s_load_dwordx16 %0, %2, 0\n\t"                              \
                 "s_load_dwordx16 %1, %2, 64"                                 \
                 : "=s"(B0), "=s"(B1) : "s"(_sp));                            \
} while (0)

// wait for all outstanding lgkm (pending s_loads + prior ds_write);
// "+s" ties make every consumer of B0/B1 data-dependent on this wait.
#define WWAIT(B0, B1)                                                         \
    asm volatile("s_waitcnt lgkmcnt(0)" : "+s"(B0), "+s"(B1))

// one pair-op: J is a LITERAL index 0..7 (shufflevector needs parse-time ICE)
#define WOP(WL, J, MVI, ACC) do {                                             \
    f32x2 wp = __builtin_shufflevector(WL, WL, 2 * (J), 2 * (J) + 1);         \
    ACC = fma2(wp, Mv2[MVI], ACC);                                            \
    f32x2 t1 = fma2(ne2, Mv2[MVI], a2);                                       \
    Mv2[MVI] = fma2(wp, t1, Mv2[MVI]);                                        \
} while (0)

// one chain step; w pairs come straight from the SGPR tuples
#define STEPW(WL0, WL1, ER, tl) do {                                          \
    unsigned ea = u4get(ER[(tl) >> 2], (tl) & 3);                             \
    float e  = __uint_as_float(ea << 16);                                     \
    float av = __uint_as_float(ea & 0xffff0000u);                             \
    f32x2 ne2 = mk2(-e, -e);                                                  \
    f32x2 a2  = mk2(av, av);                                                  \
    f32x2 racc0 = mk2(0.f, 0.f), racc1 = racc0, racc2 = racc0, racc3 = racc0; \
    WOP(WL0, 0, 0, racc0);  WOP(WL0, 1, 1, racc1);                            \
    WOP(WL0, 2, 2, racc2);  WOP(WL0, 3, 3, racc3);                            \
    WOP(WL0, 4, 4, racc0);  WOP(WL0, 5, 5, racc1);                            \
    WOP(WL0, 6, 6, racc2);  WOP(WL0, 7, 7, racc3);                            \
    WOP(WL1, 0, 8, racc0);  WOP(WL1, 1, 9, racc1);                            \
    WOP(WL1, 2, 10, racc2); WOP(WL1, 3, 11, racc3);                           \
    WOP(WL1, 4, 12, racc0); WOP(WL1, 5, 13, racc1);                           \
    WOP(WL1, 6, 14, racc2); WOP(WL1, 7, 15, racc3);                           \
    f32x2 rs = (racc0 + racc1) + (racc2 + racc3);                             \
    slp[(tl) * RSTR + tid] = f2bf(rs.x + rs.y);                               \
} while (0)

// chunk: wait(cur) -> issue prefetch(next) -> compute(cur), ping-pong A/B
#define SEQ_CHUNKW(ER, gg, SL) do {                                           \
    unsigned short* slp = SL;                                                 \
    _Pragma("unroll")                                                         \
    for (int tp = 0; tp < 16; ++tp) {                                         \
        int gs = (gg) * 32 + 2 * tp;                                          \
        WWAIT(wA0, wA1);                                                      \
        WLOAD(wB0, wB1, gs + 1);                                              \
        STEPW(wA0, wA1, ER, 2 * tp);                                          \
        WWAIT(wB0, wB1);                                                      \
        WLOAD(wA0, wA1, gs + 2);                                              \
        STEPW(wB0, wB1, ER, 2 * tp + 1);                                      \
    }                                                                         \
} while (0)

__device__ __forceinline__ void consume_chunk(
    int gc, const unsigned short* sl, const unsigned short* fWl,
    int b, int Tc, int t0,
    const unsigned short* __restrict__ Ko, const float* __restrict__ pW,
    float pbv, float* __restrict__ pred, int tid)
{
    const int lane = tid & 63;
    const int cw = (tid >> 6) & 1;          // consumer wave 0/1 -> rows cw*16..+15
    const int mrow = lane & 15, quad = lane >> 4;
    s16x8 aF[4];
#pragma unroll
    for (int kb = 0; kb < 4; ++kb)
        aF[kb] = *(const s16x8*)&sl[(cw * 16 + mrow) * RSTR + kb * 32 + quad * 8];
    float p0 = 0.f, p1 = 0.f, p2 = 0.f, p3 = 0.f;
    size_t rbase = (size_t)b * Tc + gc * CH + cw * 16 + quad * 4;
#pragma unroll
    for (int nt = 0; nt < 8; ++nt) {
        f32x4 acc = {0.f, 0.f, 0.f, 0.f};
#pragma unroll
        for (int kb = 0; kb < 4; ++kb) {
            s16x8 bf = *(const s16x8*)&fWl[(nt * 16 + mrow) * RSTR + kb * 32 + quad * 8];
            acc = __builtin_amdgcn_mfma_f32_16x16x32_bf16(aF[kb], bf, acc, 0, 0, 0);
        }
        int col = nt * 16 + mrow;
        float pw = pW[col];
        p0 = fmaf(fast_tanh(acc[0] + bf2f(Ko[(rbase + 0) * 128 + col])), pw, p0);
        p1 = fmaf(fast_tanh(acc[1] + bf2f(Ko[(rbase + 1) * 128 + col])), pw, p1);
        p2 = fmaf(fast_tanh(acc[2] + bf2f(Ko[(rbase + 2) * 128 + col])), pw, p2);
        p3 = fmaf(fast_tanh(acc[3] + bf2f(Ko[(rbase + 3) * 128 + col])), pw, p3);
    }
#pragma unroll
    for (int off = 1; off < 16; off <<= 1) {
        p0 += __shfl_xor(p0, off, 64); p1 += __shfl_xor(p1, off, 64);
        p2 += __shfl_xor(p2, off, 64); p3 += __shfl_xor(p3, off, 64);
    }
    if (mrow == 0) {
        int tb = t0 + gc * CH + cw * 16 + quad * 4;
        float ps[4] = {p0, p1, p2, p3};
#pragma unroll
        for (int reg = 0; reg < 4; ++reg) {
            int t = tb + reg;
            if (t < TT - 1) pred[b * (TT - 1) + t] = fast_sigmoid(ps[reg] + pbv);
        }
    }
}

__global__ __launch_bounds__(256, 1) void fused_kernel(
    const float* __restrict__ W, const unsigned* __restrict__ EA,
    const float* __restrict__ Mv0, const unsigned short* __restrict__ Ko,
    const unsigned short* __restrict__ fWat, const float* __restrict__ pW,
    const float* __restrict__ pb,
    float* __restrict__ pred, float* __restrict__ MvWS,
    int t0, int Tc, int doInit, int doSave)
{
    const int b = blockIdx.x;
    const int tid = threadIdx.x;
    const int nch = Tc / CH;
    // wave-uniform producer/consumer predicate: readfirstlane makes it
    // UNIFORM to divergence analysis -> scalar branch, uniform PHIs.
    const int prod = (__builtin_amdgcn_readfirstlane(tid) >> 7) == 0;

    __shared__ __align__(16) unsigned short rtl[2][CH * RSTR];  // 17.4 KB
    __shared__ __align__(16) unsigned short fWl[128 * RSTR];    // 34.8 KB

    // stage fWat -> fWl (all 256 threads)
    {
        int n = tid >> 1, k0 = (tid & 1) * 64;
#pragma unroll
        for (int j = 0; j < 8; ++j)
            *(s16x8*)&fWl[n * RSTR + k0 + j * 8] = *(const s16x8*)&fWat[n * 128 + k0 + j * 8];
    }

    const float* __restrict__ Wb = W + (size_t)b * Tc * 32;
    const uint4* __restrict__ EA4 = (const uint4*)EA;
    const int bq = b * nch;
    f32x2 Mv2[16];
    f32x16 wA0, wA1, wB0, wB1;
    uint4 erA[8], erB[8];
    float pbv = 0.f;

    if (prod) {
        if (doInit) {
#pragma unroll
            for (int i = 0; i < 16; ++i)
                Mv2[i] = mk2(Mv0[(2 * i) * 128 + tid], Mv0[(2 * i + 1) * 128 + tid]);
        } else {
#pragma unroll
            for (int i = 0; i < 16; ++i)
                Mv2[i] = mk2(MvWS[(size_t)b * 4096 + (2 * i) * 128 + tid],
                             MvWS[(size_t)b * 4096 + (2 * i + 1) * 128 + tid]);
        }
        WLOAD(wA0, wA1, 0);
        LOAD_EA(erA, 0);
    } else {
        pbv = pb[0];
        // warm the block's W strip (Tc*32 floats = Tc*8 float4) into the
        // local XCD L2 so producer s_loads are L2 hits, not L3.
        const float4* Wt4 = (const float4*)Wb;
        int j = tid - 128;
#pragma unroll 4
        for (; j < Tc * 8; j += 128) {
            float4 tch = Wt4[j];
            asm volatile("" :: "v"(tch.x), "v"(tch.y), "v"(tch.z), "v"(tch.w));
        }
    }
    __syncthreads();

    for (int g = 0; g < nch; g += 2) {
        // ---- even chunk g: produce -> slot0; consume chunk g-1 (slot1) ----
        if (prod) {
            if (g + 1 < nch) LOAD_EA(erB, g + 1);
            SEQ_CHUNKW(erA, g, rtl[0]);
        } else if (g >= 1) {
            consume_chunk(g - 1, rtl[1], fWl, b, Tc, t0, Ko, pW, pbv, pred, tid);
        }
        __syncthreads();

        // ---- odd chunk g+1: produce -> slot1; consume chunk g (slot0) ----
        if (prod) {
            if (g + 1 < nch) {
                if (g + 2 < nch) LOAD_EA(erA, g + 2);
                SEQ_CHUNKW(erB, g + 1, rtl[1]);
            }
        } else {
            consume_chunk(g, rtl[0], fWl, b, Tc, t0, Ko, pW, pbv, pred, tid);
        }
        __syncthreads();
    }
    // epilogue: for even nch the last (odd) chunk is still unconsumed
    if (!(nch & 1) && !prod) {
        consume_chunk(nch - 1, rtl[1], fWl, b, Tc, t0, Ko, pW, pbv, pred, tid);
    }

    if (doSave && prod) {
#pragma unroll
        for (int i = 0; i < 16; ++i) {
            MvWS[(size_t)b * 4096 + (2 * i) * 128 + tid]     = Mv2[i].x;
            MvWS[(size_t)b * 4096 + (2 * i + 1) * 128 + tid] = Mv2[i].y;
        }
    }
}

// ---------------------------------------------------------------------------

extern "C" void kernel_launch(void* const* d_in, const int* in_sizes, int n_in,
                              void* d_out, int out_size, void* d_ws, size_t ws_size,
                              hipStream_t stream) {
    const int*   skills    = (const int*)d_in[0];
    const int*   responses = (const int*)d_in[1];
    const float* k_emb     = (const float*)d_in[2];
    const float* v_emb     = (const float*)d_in[3];
    const float* Mk        = (const float*)d_in[4];
    const float* Mv0       = (const float*)d_in[5];
    const float* f_W       = (const float*)d_in[6];
    const float* f_b       = (const float*)d_in[7];
    const float* p_W       = (const float*)d_in[8];
    const float* p_b       = (const float*)d_in[9];
    const float* e_W       = (const float*)d_in[10];
    const float* e_b       = (const float*)d_in[11];
    const float* a_W       = (const float*)d_in[12];
    const float* a_b       = (const float*)d_in[13];

    float* pred    = (float*)d_out;                 // [256][255]
    float* outTrue = pred + BB * (TT - 1);          // [256][255]

    // scratch per row: Wo 128 B + EA 512 B + Ko 256 B = 896 B
    int Tc = TT;
    for (;;) {
        size_t need = (size_t)BB * Tc * 896 + 69632 * 2;
        if (Tc < TT) need += (size_t)BB * 4096 * 4;
        if (need <= ws_size || Tc <= 32) break;
        Tc >>= 1;
    }

    char* p = (char*)d_ws;
    float* Wo = (float*)p;                     p += (size_t)BB * Tc * 32 * 4;
    unsigned* EA = (unsigned*)p;               p += (size_t)BB * Tc * 128 * 4;
    unsigned short* Ko = (unsigned short*)p;   p += (size_t)BB * Tc * 128 * 2;
    unsigned short* eWt = (unsigned short*)p;  p += 16384 * 2;
    unsigned short* aWt = (unsigned short*)p;  p += 16384 * 2;
    unsigned short* fWat = (unsigned short*)p; p += 16384 * 2;
    unsigned short* fWbt = (unsigned short*)p; p += 16384 * 2;
    unsigned short* Mkt = (unsigned short*)p;  p += 4096 * 2;
    float* MvWS = (float*)p;

    conv_kernel<<<272, 256, 0, stream>>>(e_W, a_W, f_W, Mk,
                                         eWt, aWt, fWat, fWbt, Mkt);

    for (int t0 = 0; t0 < TT; t0 += Tc) {
        pre_kernel<<<(BB * Tc) / 64, 256, 0, stream>>>(
            skills, responses, k_emb, v_emb, f_b, e_b, a_b,
            Mkt, fWbt, eWt, aWt, Wo, EA, Ko, outTrue, t0, Tc);
        fused_kernel<<<BB, 256, 0, stream>>>(
            Wo, EA, Mv0, Ko, fWat, p_W, p_b, pred, MvWS,
            t0, Tc, t0 == 0 ? 1 : 0, (t0 + Tc < TT) ? 1 : 0);
    }
}

// Round 6
// 202.321 us; speedup vs baseline: 1.0369x; 1.0369x over previous
//
#include <hip/hip_runtime.h>
#include <math.h>

// Problem constants (fixed by setup_inputs)
#define BB 256      // batch
#define TT 256      // time steps
#define NQ 1000     // num_q
#define DK 128
#define DV 128
#define CC 32

typedef short s16x8 __attribute__((ext_vector_type(8)));   // 8 bf16 bit-patterns
typedef float f32x4 __attribute__((ext_vector_type(4)));
typedef float f32x2 __attribute__((ext_vector_type(2)));

__device__ __forceinline__ float fast_sigmoid(float x) {
    x = fminf(fmaxf(x, -30.f), 30.f);
    return 1.f / (1.f + __expf(-x));
}
__device__ __forceinline__ float fast_tanh(float x) {
    x = fminf(fmaxf(x, -15.f), 15.f);
    float t = __expf(2.f * x);
    return (t - 1.f) / (t + 1.f);
}
__device__ __forceinline__ unsigned short f2bf(float f) {   // RNE fp32->bf16
    unsigned u = __float_as_uint(f);
    u += 0x7fffu + ((u >> 16) & 1u);
    return (unsigned short)(u >> 16);
}
__device__ __forceinline__ float bf2f(unsigned short h) {
    return __uint_as_float((unsigned)h << 16);
}
__device__ __forceinline__ unsigned u4get(uint4 v, int i) { // i constant after unroll
    return i == 0 ? v.x : i == 1 ? v.y : i == 2 ? v.z : v.w;
}
__device__ __forceinline__ f32x2 mk2(float x, float y) { f32x2 r; r.x = x; r.y = y; return r; }
__device__ __forceinline__ f32x2 fma2(f32x2 a, f32x2 b, f32x2 c) {
    return __builtin_elementwise_fma(a, b, c);
}
__device__ __forceinline__ s16x8 cvt8(float4 v0, float4 v1) {
    s16x8 f;
    f[0] = (short)f2bf(v0.x); f[1] = (short)f2bf(v0.y);
    f[2] = (short)f2bf(v0.z); f[3] = (short)f2bf(v0.w);
    f[4] = (short)f2bf(v1.x); f[5] = (short)f2bf(v1.y);
    f[6] = (short)f2bf(v1.z); f[7] = (short)f2bf(v1.w);
    return f;
}

// ---------------------------------------------------------------------------
// conv_kernel: build bf16 TRANSPOSED weights in ws (B-operand layout Wt[n][k])
// ---------------------------------------------------------------------------
__global__ __launch_bounds__(256) void conv_kernel(
    const float* __restrict__ eW, const float* __restrict__ aW,
    const float* __restrict__ fW, const float* __restrict__ Mk,
    unsigned short* __restrict__ eWt, unsigned short* __restrict__ aWt,
    unsigned short* __restrict__ fWat, unsigned short* __restrict__ fWbt,
    unsigned short* __restrict__ Mkt)
{
    int idx = blockIdx.x * 256 + threadIdx.x;
    if (idx < 16384) {
        int n = idx >> 7, k = idx & 127;
        eWt[idx] = f2bf(eW[k * 128 + n]);
    } else if (idx < 32768) {
        int i = idx - 16384; int n = i >> 7, k = i & 127;
        aWt[i] = f2bf(aW[k * 128 + n]);
    } else if (idx < 49152) {
        int i = idx - 32768; int n = i >> 7, k = i & 127;
        fWat[i] = f2bf(fW[k * 128 + n]);
    } else if (idx < 65536) {
        int i = idx - 49152; int n = i >> 7, k = i & 127;
        fWbt[i] = f2bf(fW[(128 + k) * 128 + n]);
    } else if (idx < 69632) {
        int i = idx - 65536; int n = i >> 7, k = i & 127;   // n=c 0..31
        Mkt[i] = f2bf(Mk[k * 32 + n]);
    }
}

// ---------------------------------------------------------------------------
// pre_kernel v2 (R11): same math, data movement minimized.
// ---------------------------------------------------------------------------
__global__ __launch_bounds__(256) void pre_kernel(
    const int* __restrict__ skills, const int* __restrict__ responses,
    const float* __restrict__ k_emb, const float* __restrict__ v_emb,
    const float* __restrict__ fb, const float* __restrict__ eb,
    const float* __restrict__ ab,
    const unsigned short* __restrict__ Mkt, const unsigned short* __restrict__ fWbt,
    const unsigned short* __restrict__ eWt, const unsigned short* __restrict__ aWt,
    float* __restrict__ Wo, unsigned* __restrict__ EA,
    unsigned short* __restrict__ Ko, float* __restrict__ outTrue,
    int t0, int Tc)
{
    const int tid = threadIdx.x;
    const int lane = tid & 63;
    const int m_base = (tid >> 6) * 16;
    const int mrow = lane & 15, quad = lane >> 4;
    const size_t base = (size_t)blockIdx.x * 64;

    __shared__ __align__(16) unsigned short Wlds[128 * 136];   // 34.8 KB

    // per-lane gather row (A-side): row = base + m_base + mrow
    int grow = (int)base + m_base + mrow;
    int gb = grow / Tc;
    int gt = t0 + (grow - gb * Tc);
    int gi = gb * TT + gt;
    int s = skills[gi];
    int r = responses[gi];
    int q = s + NQ * ((r > -1) ? r : 0);
    if (quad == 0 && gt >= 1) outTrue[gb * (TT - 1) + (gt - 1)] = (float)r;

    // stage Mkt rows 0..31
    {
        int n = tid >> 3, k0 = (tid & 7) * 16;
        *(s16x8*)&Wlds[n * 136 + k0]     = *(const s16x8*)&Mkt[n * 128 + k0];
        *(s16x8*)&Wlds[n * 136 + k0 + 8] = *(const s16x8*)&Mkt[n * 128 + k0 + 8];
    }

    // gather kt A-frags direct to regs: aF[kb] = kt[row][kb*32 + quad*8 ..+7]
    s16x8 aF[4];
    {
        const float* kr = k_emb + (size_t)s * DK + quad * 8;
#pragma unroll
        for (int kb = 0; kb < 4; ++kb)
            aF[kb] = cvt8(*(const float4*)(kr + kb * 32),
                          *(const float4*)(kr + kb * 32 + 4));
    }
    __syncthreads();   // [1] Mkt staged

    // logits (NT=2) + in-register softmax -> Wo
    {
        f32x4 l0 = {0.f, 0.f, 0.f, 0.f}, l1 = {0.f, 0.f, 0.f, 0.f};
#pragma unroll
        for (int kb = 0; kb < 4; ++kb) {
            s16x8 b0 = *(const s16x8*)&Wlds[mrow * 136 + kb * 32 + quad * 8];
            s16x8 b1 = *(const s16x8*)&Wlds[(16 + mrow) * 136 + kb * 32 + quad * 8];
            l0 = __builtin_amdgcn_mfma_f32_16x16x32_bf16(aF[kb], b0, l0, 0, 0, 0);
            l1 = __builtin_amdgcn_mfma_f32_16x16x32_bf16(aF[kb], b1, l1, 0, 0, 0);
        }
        // lane holds cols {mrow, 16+mrow} for rows m_base + quad*4 + reg
#pragma unroll
        for (int reg = 0; reg < 4; ++reg) {
            float a0 = l0[reg], a1 = l1[reg];
            float m = fmaxf(a0, a1);
#pragma unroll
            for (int off = 1; off < 16; off <<= 1)
                m = fmaxf(m, __shfl_xor(m, off, 64));
            float e0 = __expf(a0 - m), e1 = __expf(a1 - m);
            float ssum = e0 + e1;
#pragma unroll
            for (int off = 1; off < 16; off <<= 1)
                ssum += __shfl_xor(ssum, off, 64);
            float inv = 1.f / ssum;
            size_t rowg = base + m_base + quad * 4 + reg;
            Wo[rowg * 32 + mrow]      = e0 * inv;
            Wo[rowg * 32 + 16 + mrow] = e1 * inv;
        }
    }
    __syncthreads();   // [2] logits' Wlds reads done

    // stage fWbt
    {
        int n = tid >> 1, k0 = (tid & 1) * 64;
#pragma unroll
        for (int j = 0; j < 8; ++j)
            *(s16x8*)&Wlds[n * 136 + k0 + j * 8] = *(const s16x8*)&fWbt[n * 128 + k0 + j * 8];
    }
    __syncthreads();   // [3]

    // gather vt frags early (global latency overlaps ck MFMA below)
    s16x8 vF[4];
    {
        const float* vr = v_emb + (size_t)q * DV + quad * 8;
#pragma unroll
        for (int kb = 0; kb < 4; ++kb)
            vF[kb] = cvt8(*(const float4*)(vr + kb * 32),
                          *(const float4*)(vr + kb * 32 + 4));
    }

    // ck = kt@fWb + fb -> Ko
#pragma unroll
    for (int nt = 0; nt < 8; ++nt) {
        f32x4 acc = {0.f, 0.f, 0.f, 0.f};
#pragma unroll
        for (int kb = 0; kb < 4; ++kb) {
            s16x8 bf = *(const s16x8*)&Wlds[(nt * 16 + mrow) * 136 + kb * 32 + quad * 8];
            acc = __builtin_amdgcn_mfma_f32_16x16x32_bf16(aF[kb], bf, acc, 0, 0, 0);
        }
        int col = nt * 16 + mrow;
        float fbv = fb[col];
#pragma unroll
        for (int reg = 0; reg < 4; ++reg) {
            size_t rr = base + m_base + quad * 4 + reg;
            Ko[rr * 128 + col] = f2bf(acc[reg] + fbv);
        }
    }
    __syncthreads();   // [4] ck's Wlds reads done

    // stage eWt
    {
        int n = tid >> 1, k0 = (tid & 1) * 64;
#pragma unroll
        for (int j = 0; j < 8; ++j)
            *(s16x8*)&Wlds[n * 136 + k0 + j * 8] = *(const s16x8*)&eWt[n * 128 + k0 + j * 8];
    }
    __syncthreads();   // [5]

    // et = sigmoid(vt@eW + eb) -> registers
    float etr[8][4];
#pragma unroll
    for (int nt = 0; nt < 8; ++nt) {
        f32x4 acc = {0.f, 0.f, 0.f, 0.f};
#pragma unroll
        for (int kb = 0; kb < 4; ++kb) {
            s16x8 bf = *(const s16x8*)&Wlds[(nt * 16 + mrow) * 136 + kb * 32 + quad * 8];
            acc = __builtin_amdgcn_mfma_f32_16x16x32_bf16(vF[kb], bf, acc, 0, 0, 0);
        }
        int col = nt * 16 + mrow;
        float ebv = eb[col];
#pragma unroll
        for (int reg = 0; reg < 4; ++reg)
            etr[nt][reg] = fast_sigmoid(acc[reg] + ebv);
    }
    __syncthreads();   // [6] et's Wlds reads done

    // stage aWt
    {
        int n = tid >> 1, k0 = (tid & 1) * 64;
#pragma unroll
        for (int j = 0; j < 8; ++j)
            *(s16x8*)&Wlds[n * 136 + k0 + j * 8] = *(const s16x8*)&aWt[n * 128 + k0 + j * 8];
    }
    __syncthreads();   // [7]

    // at = tanh(vt@aW + ab); pack (et,at) -> EA
#pragma unroll
    for (int nt = 0; nt < 8; ++nt) {
        f32x4 acc = {0.f, 0.f, 0.f, 0.f};
#pragma unroll
        for (int kb = 0; kb < 4; ++kb) {
            s16x8 bf = *(const s16x8*)&Wlds[(nt * 16 + mrow) * 136 + kb * 32 + quad * 8];
            acc = __builtin_amdgcn_mfma_f32_16x16x32_bf16(vF[kb], bf, acc, 0, 0, 0);
        }
        int col = nt * 16 + mrow;
        float abv = ab[col];
#pragma unroll
        for (int reg = 0; reg < 4; ++reg) {
            size_t rr = base + m_base + quad * 4 + reg;
            int bb = (int)(rr / (size_t)Tc);
            int t  = (int)(rr - (size_t)bb * Tc);
            size_t o4 = (((size_t)bb * (Tc >> 5) + (t >> 5)) * 8 + ((t >> 2) & 7)) * 128 + col;
            unsigned lo = f2bf(etr[nt][reg]);
            unsigned hi = (unsigned)f2bf(fast_tanh(acc[reg] + abv)) << 16;
            EA[o4 * 4 + (t & 3)] = hi | lo;
        }
    }
}

// ---------------------------------------------------------------------------
// fused_kernel v10 (seq + post) — R16:
//  SMEM path abandoned (R5: s_load L2 latency ~400cyc not coverable at
//  dist-1; SGPR cap blocks deeper). Back to the R1 LDS/VALU design but with
//  the producer LANE-PAIR SPLIT: all 256 threads produce. Thread (d,h) =
//  (tid>>1, tid&1) owns Mv columns c = h*16..h*16+15 of column d. Per-step
//  per-thread issue HALVES (24 fma2 + 4 ds_read vs 48 + 8); dot product
//  rejoined with one __shfl_xor(sum,1) (DPP, adjacent lanes same wave).
//  Consume runs as a short serialized phase on waves 0-1 while waves 2-3
//  stage the next W chunk. er/Wl/rtl single-buffered (phases now barrier-
//  separated): LDS 61.4 -> 48.1 KB, -32 VGPR er double-buffer.
// ---------------------------------------------------------------------------

#define CH 32
#define WROW 36     // Wl row stride (floats)
#define RSTR 136    // rtl/fWl row stride (shorts)
#define SB() __builtin_amdgcn_sched_barrier(0)

#define LOAD_W(gg) do {                                                       \
    const float* ws = Wb + (size_t)(gg) * CH * 32;                            \
    int t2 = tid & 127;                                                       \
    wr0 = *(const float4*)(ws + t2 * 8);                                      \
    wr1 = *(const float4*)(ws + t2 * 8 + 4);                                  \
} while (0)

#define PUB_W() do {                                                          \
    float* wd = &Wl[lr * WROW + lq * 8];                                      \
    *(float4*)wd = wr0; *(float4*)(wd + 4) = wr1;                             \
} while (0)

// all threads: er for chunk gg, thread's own column dd
#define LOAD_EA(ER, gg) do {                                                  \
    const uint4* src = EA4 + ((size_t)(bq + (gg))) * 1024 + dd;               \
    _Pragma("unroll")                                                         \
    for (int j = 0; j < 8; ++j) ER[j] = src[j * 128];                         \
} while (0)

// prefetch this thread's 16 w floats (c = hh*16 ..+15) of row `rowidx`
#define PREF4(A0,A1,A2,A3, rowidx) do {                                       \
    const float* _wr = wlc + (rowidx) * WROW;                                 \
    A0 = *(const float4*)(_wr + 0);  A1 = *(const float4*)(_wr + 4);          \
    A2 = *(const float4*)(_wr + 8);  A3 = *(const float4*)(_wr + 12);         \
} while (0)

// one chain step on this thread's 8 c-pairs; lane-pair reduce for the dot
#define STEP4(A0,A1,A2,A3, ER, tl) do {                                       \
    f32x2 w2[8];                                                              \
    w2[0] = mk2(A0.x, A0.y); w2[1] = mk2(A0.z, A0.w);                         \
    w2[2] = mk2(A1.x, A1.y); w2[3] = mk2(A1.z, A1.w);                         \
    w2[4] = mk2(A2.x, A2.y); w2[5] = mk2(A2.z, A2.w);                         \
    w2[6] = mk2(A3.x, A3.y); w2[7] = mk2(A3.z, A3.w);                         \
    unsigned ea = u4get(ER[(tl) >> 2], (tl) & 3);                             \
    float e  = __uint_as_float(ea << 16);                                     \
    float av = __uint_as_float(ea & 0xffff0000u);                             \
    f32x2 ne2 = mk2(-e, -e);                                                  \
    f32x2 a2  = mk2(av, av);                                                  \
    f32x2 r0 = mk2(0.f, 0.f), r1 = r0, r2 = r0, r3 = r0;                      \
    r0 = fma2(w2[0], Mv2[0], r0); r1 = fma2(w2[1], Mv2[1], r1);               \
    r2 = fma2(w2[2], Mv2[2], r2); r3 = fma2(w2[3], Mv2[3], r3);               \
    r0 = fma2(w2[4], Mv2[4], r0); r1 = fma2(w2[5], Mv2[5], r1);               \
    r2 = fma2(w2[6], Mv2[6], r2); r3 = fma2(w2[7], Mv2[7], r3);               \
    f32x2 rs = (r0 + r1) + (r2 + r3);                                         \
    float sum = rs.x + rs.y;                                                  \
    sum += __shfl_xor(sum, 1, 64);                                            \
    slp[(tl) * RSTR + dd] = f2bf(sum);  /* both lanes, same value: benign */  \
    _Pragma("unroll")                                                         \
    for (int i = 0; i < 8; ++i)                                               \
        Mv2[i] = fma2(w2[i], fma2(ne2, Mv2[i], a2), Mv2[i]);                  \
} while (0)

// chunk with sched_barrier-pinned 1-step-ahead w pipeline
#define SEQ_CHUNK4(ER, gg, SL) do {                                           \
    const float* wlc = Wl + hh * 16;                                          \
    unsigned short* slp = SL;                                                 \
    PREF4(w0, w1, w2_, w3_, 0);                                               \
    _Pragma("unroll")                                                         \
    for (int tp = 0; tp < 16; ++tp) {                                         \
        SB(); PREF4(u0, u1, u2, u3, 2 * tp + 1); SB();                        \
        STEP4(w0, w1, w2_, w3_, ER, 2 * tp);                                  \
        SB(); PREF4(w0, w1, w2_, w3_,                                         \
                    (2 * tp + 2 < 32) ? (2 * tp + 2) : 31); SB();             \
        STEP4(u0, u1, u2, u3, ER, 2 * tp + 1);                                \
    }                                                                         \
} while (0)

__device__ __forceinline__ void consume_chunk(
    int gc, const unsigned short* sl, const unsigned short* fWl,
    int b, int Tc, int t0,
    const unsigned short* __restrict__ Ko, const float* __restrict__ pW,
    float pbv, float* __restrict__ pred, int tid)
{
    const int lane = tid & 63;
    const int cw = (tid >> 6) & 1;          // consumer wave 0/1 -> rows cw*16..+15
    const int mrow = lane & 15, quad = lane >> 4;
    s16x8 aF[4];
#pragma unroll
    for (int kb = 0; kb < 4; ++kb)
        aF[kb] = *(const s16x8*)&sl[(cw * 16 + mrow) * RSTR + kb * 32 + quad * 8];
    float p0 = 0.f, p1 = 0.f, p2 = 0.f, p3 = 0.f;
    size_t rbase = (size_t)b * Tc + gc * CH + cw * 16 + quad * 4;
#pragma unroll
    for (int nt = 0; nt < 8; ++nt) {
        f32x4 acc = {0.f, 0.f, 0.f, 0.f};
#pragma unroll
        for (int kb = 0; kb < 4; ++kb) {
            s16x8 bf = *(const s16x8*)&fWl[(nt * 16 + mrow) * RSTR + kb * 32 + quad * 8];
            acc = __builtin_amdgcn_mfma_f32_16x16x32_bf16(aF[kb], bf, acc, 0, 0, 0);
        }
        int col = nt * 16 + mrow;
        float pw = pW[col];
        p0 = fmaf(fast_tanh(acc[0] + bf2f(Ko[(rbase + 0) * 128 + col])), pw, p0);
        p1 = fmaf(fast_tanh(acc[1] + bf2f(Ko[(rbase + 1) * 128 + col])), pw, p1);
        p2 = fmaf(fast_tanh(acc[2] + bf2f(Ko[(rbase + 2) * 128 + col])), pw, p2);
        p3 = fmaf(fast_tanh(acc[3] + bf2f(Ko[(rbase + 3) * 128 + col])), pw, p3);
    }
#pragma unroll
    for (int off = 1; off < 16; off <<= 1) {
        p0 += __shfl_xor(p0, off, 64); p1 += __shfl_xor(p1, off, 64);
        p2 += __shfl_xor(p2, off, 64); p3 += __shfl_xor(p3, off, 64);
    }
    if (mrow == 0) {
        int tb = t0 + gc * CH + cw * 16 + quad * 4;
        float ps[4] = {p0, p1, p2, p3};
#pragma unroll
        for (int reg = 0; reg < 4; ++reg) {
            int t = tb + reg;
            if (t < TT - 1) pred[b * (TT - 1) + t] = fast_sigmoid(ps[reg] + pbv);
        }
    }
}

__global__ __launch_bounds__(256, 1) void fused_kernel(
    const float* __restrict__ W, const unsigned* __restrict__ EA,
    const float* __restrict__ Mv0, const unsigned short* __restrict__ Ko,
    const unsigned short* __restrict__ fWat, const float* __restrict__ pW,
    const float* __restrict__ pb,
    float* __restrict__ pred, float* __restrict__ MvWS,
    int t0, int Tc, int doInit, int doSave)
{
    const int b = blockIdx.x;
    const int tid = threadIdx.x;
    const int nch = Tc / CH;
    const int dd = tid >> 1;        // owned Mv column d (0..127)
    const int hh = tid & 1;         // c-half: c = hh*16 .. hh*16+15

    __shared__ __align__(16) float Wl[CH * WROW];               //  4.6 KB
    __shared__ __align__(16) unsigned short rtl[CH * RSTR];     //  8.7 KB
    __shared__ __align__(16) unsigned short fWl[128 * RSTR];    // 34.8 KB

    // stage fWat -> fWl (all 256 threads)
    {
        int n = tid >> 1, k0 = (tid & 1) * 64;
#pragma unroll
        for (int j = 0; j < 8; ++j)
            *(s16x8*)&fWl[n * RSTR + k0 + j * 8] = *(const s16x8*)&fWat[n * 128 + k0 + j * 8];
    }

    const int lr = (tid & 127) >> 2, lq = tid & 3;
    const float* __restrict__ Wb = W + (size_t)b * Tc * 32;
    const uint4* __restrict__ EA4 = (const uint4*)EA;
    const int bq = b * nch;
    f32x2 Mv2[8];
    float4 wr0, wr1;
    float4 w0, w1, w2_, w3_;
    float4 u0, u1, u2, u3;
    uint4 erA[8];
    float pbv = pb[0];

    if (tid >= 128) LOAD_W(0);

    // Mv init: thread (dd,hh) holds c = hh*16+2i, +1 for i=0..7
    if (doInit) {
#pragma unroll
        for (int i = 0; i < 8; ++i)
            Mv2[i] = mk2(Mv0[(hh * 16 + 2 * i) * 128 + dd],
                         Mv0[(hh * 16 + 2 * i + 1) * 128 + dd]);
    } else {
#pragma unroll
        for (int i = 0; i < 8; ++i)
            Mv2[i] = mk2(MvWS[(size_t)b * 4096 + (hh * 16 + 2 * i) * 128 + dd],
                         MvWS[(size_t)b * 4096 + (hh * 16 + 2 * i + 1) * 128 + dd]);
    }
    LOAD_EA(erA, 0);
    if (tid >= 128) {
        PUB_W();
        if (nch > 1) LOAD_W(1);
    }
    __syncthreads();

    for (int g = 0; g < nch; ++g) {
        SEQ_CHUNK4(erA, g, rtl);                 // all 256 threads produce
        __syncthreads();
        if (g + 1 < nch) LOAD_EA(erA, g + 1);    // HBM latency hides under consume
        if (tid < 128) {
            consume_chunk(g, rtl, fWl, b, Tc, t0, Ko, pW, pbv, pred, tid);
        } else if (g + 1 < nch) {
            PUB_W();                             // Wl for chunk g+1
            if (g + 2 < nch) LOAD_W(g + 2);
        }
        __syncthreads();
    }

    if (doSave) {
#pragma unroll
        for (int i = 0; i < 8; ++i) {
            MvWS[(size_t)b * 4096 + (hh * 16 + 2 * i) * 128 + dd]     = Mv2[i].x;
            MvWS[(size_t)b * 4096 + (hh * 16 + 2 * i + 1) * 128 + dd] = Mv2[i].y;
        }
    }
}

// ---------------------------------------------------------------------------

extern "C" void kernel_launch(void* const* d_in, const int* in_sizes, int n_in,
                              void* d_out, int out_size, void* d_ws, size_t ws_size,
                              hipStream_t stream) {
    const int*   skills    = (const int*)d_in[0];
    const int*   responses = (const int*)d_in[1];
    const float* k_emb     = (const float*)d_in[2];
    const float* v_emb     = (const float*)d_in[3];
    const float* Mk        = (const float*)d_in[4];
    const float* Mv0       = (const float*)d_in[5];
    const float* f_W       = (const float*)d_in[6];
    const float* f_b       = (const float*)d_in[7];
    const float* p_W       = (const float*)d_in[8];
    const float* p_b       = (const float*)d_in[9];
    const float* e_W       = (const float*)d_in[10];
    const float* e_b       = (const float*)d_in[11];
    const float* a_W       = (const float*)d_in[12];
    const float* a_b       = (const float*)d_in[13];

    float* pred    = (float*)d_out;                 // [256][255]
    float* outTrue = pred + BB * (TT - 1);          // [256][255]

    // scratch per row: Wo 128 B + EA 512 B + Ko 256 B = 896 B
    int Tc = TT;
    for (;;) {
        size_t need = (size_t)BB * Tc * 896 + 69632 * 2;
        if (Tc < TT) need += (size_t)BB * 4096 * 4;
        if (need <= ws_size || Tc <= 32) break;
        Tc >>= 1;
    }

    char* p = (char*)d_ws;
    float* Wo = (float*)p;                     p += (size_t)BB * Tc * 32 * 4;
    unsigned* EA = (unsigned*)p;               p += (size_t)BB * Tc * 128 * 4;
    unsigned short* Ko = (unsigned short*)p;   p += (size_t)BB * Tc * 128 * 2;
    unsigned short* eWt = (unsigned short*)p;  p += 16384 * 2;
    unsigned short* aWt = (unsigned short*)p;  p += 16384 * 2;
    unsigned short* fWat = (unsigned short*)p; p += 16384 * 2;
    unsigned short* fWbt = (unsigned short*)p; p += 16384 * 2;
    unsigned short* Mkt = (unsigned short*)p;  p += 4096 * 2;
    float* MvWS = (float*)p;

    conv_kernel<<<272, 256, 0, stream>>>(e_W, a_W, f_W, Mk,
                                         eWt, aWt, fWat, fWbt, Mkt);

    for (int t0 = 0; t0 < TT; t0 += Tc) {
        pre_kernel<<<(BB * Tc) / 64, 256, 0, stream>>>(
            skills, responses, k_emb, v_emb, f_b, e_b, a_b,
            Mkt, fWbt, eWt, aWt, Wo, EA, Ko, outTrue, t0, Tc);
        fused_kernel<<<BB, 256, 0, stream>>>(
            Wo, EA, Mv0, Ko, fWat, p_W, p_b, pred, MvWS,
            t0, Tc, t0 == 0 ? 1 : 0, (t0 + Tc < TT) ? 1 : 0);
    }
}

// Round 7
// 163.422 us; speedup vs baseline: 1.2838x; 1.2380x over previous
//
#include <hip/hip_runtime.h>
#include <math.h>

// Problem constants (fixed by setup_inputs)
#define BB 256      // batch
#define TT 256      // time steps
#define NQ 1000     // num_q
#define DK 128
#define DV 128
#define CC 32

typedef short s16x8 __attribute__((ext_vector_type(8)));   // 8 bf16 bit-patterns
typedef float f32x4 __attribute__((ext_vector_type(4)));
typedef float f32x2 __attribute__((ext_vector_type(2)));

__device__ __forceinline__ float fast_sigmoid(float x) {
    x = fminf(fmaxf(x, -30.f), 30.f);
    return 1.f / (1.f + __expf(-x));
}
__device__ __forceinline__ float fast_tanh(float x) {
    x = fminf(fmaxf(x, -15.f), 15.f);
    float t = __expf(2.f * x);
    return (t - 1.f) / (t + 1.f);
}
__device__ __forceinline__ unsigned short f2bf(float f) {   // RNE fp32->bf16
    unsigned u = __float_as_uint(f);
    u += 0x7fffu + ((u >> 16) & 1u);
    return (unsigned short)(u >> 16);
}
__device__ __forceinline__ float bf2f(unsigned short h) {
    return __uint_as_float((unsigned)h << 16);
}
__device__ __forceinline__ unsigned u4get(uint4 v, int i) { // i constant after unroll
    return i == 0 ? v.x : i == 1 ? v.y : i == 2 ? v.z : v.w;
}
__device__ __forceinline__ f32x2 mk2(float x, float y) { f32x2 r; r.x = x; r.y = y; return r; }
__device__ __forceinline__ f32x2 fma2(f32x2 a, f32x2 b, f32x2 c) {
    return __builtin_elementwise_fma(a, b, c);
}
__device__ __forceinline__ s16x8 cvt8(float4 v0, float4 v1) {
    s16x8 f;
    f[0] = (short)f2bf(v0.x); f[1] = (short)f2bf(v0.y);
    f[2] = (short)f2bf(v0.z); f[3] = (short)f2bf(v0.w);
    f[4] = (short)f2bf(v1.x); f[5] = (short)f2bf(v1.y);
    f[6] = (short)f2bf(v1.z); f[7] = (short)f2bf(v1.w);
    return f;
}

// ---------------------------------------------------------------------------
// conv_kernel: build bf16 TRANSPOSED weights in ws (B-operand layout Wt[n][k])
// ---------------------------------------------------------------------------
__global__ __launch_bounds__(256) void conv_kernel(
    const float* __restrict__ eW, const float* __restrict__ aW,
    const float* __restrict__ fW, const float* __restrict__ Mk,
    unsigned short* __restrict__ eWt, unsigned short* __restrict__ aWt,
    unsigned short* __restrict__ fWat, unsigned short* __restrict__ fWbt,
    unsigned short* __restrict__ Mkt)
{
    int idx = blockIdx.x * 256 + threadIdx.x;
    if (idx < 16384) {
        int n = idx >> 7, k = idx & 127;
        eWt[idx] = f2bf(eW[k * 128 + n]);
    } else if (idx < 32768) {
        int i = idx - 16384; int n = i >> 7, k = i & 127;
        aWt[i] = f2bf(aW[k * 128 + n]);
    } else if (idx < 49152) {
        int i = idx - 32768; int n = i >> 7, k = i & 127;
        fWat[i] = f2bf(fW[k * 128 + n]);
    } else if (idx < 65536) {
        int i = idx - 49152; int n = i >> 7, k = i & 127;
        fWbt[i] = f2bf(fW[(128 + k) * 128 + n]);
    } else if (idx < 69632) {
        int i = idx - 65536; int n = i >> 7, k = i & 127;   // n=c 0..31
        Mkt[i] = f2bf(Mk[k * 32 + n]);
    }
}

// ---------------------------------------------------------------------------
// pre_kernel v2 (R11): same math, data movement minimized.
// ---------------------------------------------------------------------------
__global__ __launch_bounds__(256) void pre_kernel(
    const int* __restrict__ skills, const int* __restrict__ responses,
    const float* __restrict__ k_emb, const float* __restrict__ v_emb,
    const float* __restrict__ fb, const float* __restrict__ eb,
    const float* __restrict__ ab,
    const unsigned short* __restrict__ Mkt, const unsigned short* __restrict__ fWbt,
    const unsigned short* __restrict__ eWt, const unsigned short* __restrict__ aWt,
    float* __restrict__ Wo, unsigned* __restrict__ EA,
    unsigned short* __restrict__ Ko, float* __restrict__ outTrue,
    int t0, int Tc)
{
    const int tid = threadIdx.x;
    const int lane = tid & 63;
    const int m_base = (tid >> 6) * 16;
    const int mrow = lane & 15, quad = lane >> 4;
    const size_t base = (size_t)blockIdx.x * 64;

    __shared__ __align__(16) unsigned short Wlds[128 * 136];   // 34.8 KB

    // per-lane gather row (A-side): row = base + m_base + mrow
    int grow = (int)base + m_base + mrow;
    int gb = grow / Tc;
    int gt = t0 + (grow - gb * Tc);
    int gi = gb * TT + gt;
    int s = skills[gi];
    int r = responses[gi];
    int q = s + NQ * ((r > -1) ? r : 0);
    if (quad == 0 && gt >= 1) outTrue[gb * (TT - 1) + (gt - 1)] = (float)r;

    // stage Mkt rows 0..31
    {
        int n = tid >> 3, k0 = (tid & 7) * 16;
        *(s16x8*)&Wlds[n * 136 + k0]     = *(const s16x8*)&Mkt[n * 128 + k0];
        *(s16x8*)&Wlds[n * 136 + k0 + 8] = *(const s16x8*)&Mkt[n * 128 + k0 + 8];
    }

    // gather kt A-frags direct to regs: aF[kb] = kt[row][kb*32 + quad*8 ..+7]
    s16x8 aF[4];
    {
        const float* kr = k_emb + (size_t)s * DK + quad * 8;
#pragma unroll
        for (int kb = 0; kb < 4; ++kb)
            aF[kb] = cvt8(*(const float4*)(kr + kb * 32),
                          *(const float4*)(kr + kb * 32 + 4));
    }
    __syncthreads();   // [1] Mkt staged

    // logits (NT=2) + in-register softmax -> Wo
    {
        f32x4 l0 = {0.f, 0.f, 0.f, 0.f}, l1 = {0.f, 0.f, 0.f, 0.f};
#pragma unroll
        for (int kb = 0; kb < 4; ++kb) {
            s16x8 b0 = *(const s16x8*)&Wlds[mrow * 136 + kb * 32 + quad * 8];
            s16x8 b1 = *(const s16x8*)&Wlds[(16 + mrow) * 136 + kb * 32 + quad * 8];
            l0 = __builtin_amdgcn_mfma_f32_16x16x32_bf16(aF[kb], b0, l0, 0, 0, 0);
            l1 = __builtin_amdgcn_mfma_f32_16x16x32_bf16(aF[kb], b1, l1, 0, 0, 0);
        }
        // lane holds cols {mrow, 16+mrow} for rows m_base + quad*4 + reg
#pragma unroll
        for (int reg = 0; reg < 4; ++reg) {
            float a0 = l0[reg], a1 = l1[reg];
            float m = fmaxf(a0, a1);
#pragma unroll
            for (int off = 1; off < 16; off <<= 1)
                m = fmaxf(m, __shfl_xor(m, off, 64));
            float e0 = __expf(a0 - m), e1 = __expf(a1 - m);
            float ssum = e0 + e1;
#pragma unroll
            for (int off = 1; off < 16; off <<= 1)
                ssum += __shfl_xor(ssum, off, 64);
            float inv = 1.f / ssum;
            size_t rowg = base + m_base + quad * 4 + reg;
            Wo[rowg * 32 + mrow]      = e0 * inv;
            Wo[rowg * 32 + 16 + mrow] = e1 * inv;
        }
    }
    __syncthreads();   // [2] logits' Wlds reads done

    // stage fWbt
    {
        int n = tid >> 1, k0 = (tid & 1) * 64;
#pragma unroll
        for (int j = 0; j < 8; ++j)
            *(s16x8*)&Wlds[n * 136 + k0 + j * 8] = *(const s16x8*)&fWbt[n * 128 + k0 + j * 8];
    }
    __syncthreads();   // [3]

    // gather vt frags early (global latency overlaps ck MFMA below)
    s16x8 vF[4];
    {
        const float* vr = v_emb + (size_t)q * DV + quad * 8;
#pragma unroll
        for (int kb = 0; kb < 4; ++kb)
            vF[kb] = cvt8(*(const float4*)(vr + kb * 32),
                          *(const float4*)(vr + kb * 32 + 4));
    }

    // ck = kt@fWb + fb -> Ko
#pragma unroll
    for (int nt = 0; nt < 8; ++nt) {
        f32x4 acc = {0.f, 0.f, 0.f, 0.f};
#pragma unroll
        for (int kb = 0; kb < 4; ++kb) {
            s16x8 bf = *(const s16x8*)&Wlds[(nt * 16 + mrow) * 136 + kb * 32 + quad * 8];
            acc = __builtin_amdgcn_mfma_f32_16x16x32_bf16(aF[kb], bf, acc, 0, 0, 0);
        }
        int col = nt * 16 + mrow;
        float fbv = fb[col];
#pragma unroll
        for (int reg = 0; reg < 4; ++reg) {
            size_t rr = base + m_base + quad * 4 + reg;
            Ko[rr * 128 + col] = f2bf(acc[reg] + fbv);
        }
    }
    __syncthreads();   // [4] ck's Wlds reads done

    // stage eWt
    {
        int n = tid >> 1, k0 = (tid & 1) * 64;
#pragma unroll
        for (int j = 0; j < 8; ++j)
            *(s16x8*)&Wlds[n * 136 + k0 + j * 8] = *(const s16x8*)&eWt[n * 128 + k0 + j * 8];
    }
    __syncthreads();   // [5]

    // et = sigmoid(vt@eW + eb) -> registers
    float etr[8][4];
#pragma unroll
    for (int nt = 0; nt < 8; ++nt) {
        f32x4 acc = {0.f, 0.f, 0.f, 0.f};
#pragma unroll
        for (int kb = 0; kb < 4; ++kb) {
            s16x8 bf = *(const s16x8*)&Wlds[(nt * 16 + mrow) * 136 + kb * 32 + quad * 8];
            acc = __builtin_amdgcn_mfma_f32_16x16x32_bf16(vF[kb], bf, acc, 0, 0, 0);
        }
        int col = nt * 16 + mrow;
        float ebv = eb[col];
#pragma unroll
        for (int reg = 0; reg < 4; ++reg)
            etr[nt][reg] = fast_sigmoid(acc[reg] + ebv);
    }
    __syncthreads();   // [6] et's Wlds reads done

    // stage aWt
    {
        int n = tid >> 1, k0 = (tid & 1) * 64;
#pragma unroll
        for (int j = 0; j < 8; ++j)
            *(s16x8*)&Wlds[n * 136 + k0 + j * 8] = *(const s16x8*)&aWt[n * 128 + k0 + j * 8];
    }
    __syncthreads();   // [7]

    // at = tanh(vt@aW + ab); pack (et,at) -> EA
#pragma unroll
    for (int nt = 0; nt < 8; ++nt) {
        f32x4 acc = {0.f, 0.f, 0.f, 0.f};
#pragma unroll
        for (int kb = 0; kb < 4; ++kb) {
            s16x8 bf = *(const s16x8*)&Wlds[(nt * 16 + mrow) * 136 + kb * 32 + quad * 8];
            acc = __builtin_amdgcn_mfma_f32_16x16x32_bf16(vF[kb], bf, acc, 0, 0, 0);
        }
        int col = nt * 16 + mrow;
        float abv = ab[col];
#pragma unroll
        for (int reg = 0; reg < 4; ++reg) {
            size_t rr = base + m_base + quad * 4 + reg;
            int bb = (int)(rr / (size_t)Tc);
            int t  = (int)(rr - (size_t)bb * Tc);
            size_t o4 = (((size_t)bb * (Tc >> 5) + (t >> 5)) * 8 + ((t >> 2) & 7)) * 128 + col;
            unsigned lo = f2bf(etr[nt][reg]);
            unsigned hi = (unsigned)f2bf(fast_tanh(acc[reg] + abv)) << 16;
            EA[o4 * 4 + (t & 3)] = hi | lo;
        }
    }
}

// ---------------------------------------------------------------------------
// fused_kernel v11 (seq + post) — R17:
//  EXACT R1 (165.3 µs baseline) skeleton — overlapped producer/consumer,
//  proven best of 3 structures — with ONE change: the SB-pinned w pipeline
//  extended from distance-1 to DISTANCE-2 (4 named float4 buffer sets
//  w/u/v/x, 4-step unrolled rotation). Every STEP consumes ds_reads issued
//  2 full steps (~2x step time) earlier, covering the LDS round-trip that
//  R6 showed to be the binder (producer stall ~40%, issue-halving didn't
//  help). Nominal VGPR ~230 (<256, no spill; occupancy already 1 block/CU).
// ---------------------------------------------------------------------------

#define CH 32
#define WROW 36     // Wl row stride (floats)
#define RSTR 136    // rtl/fWl row stride (shorts)
#define SB() __builtin_amdgcn_sched_barrier(0)

#define LOAD_W(gg) do {                                                       \
    const float* ws = Wb + (size_t)(gg) * CH * 32;                            \
    wr0 = *(const float4*)(ws + tid * 8);                                     \
    wr1 = *(const float4*)(ws + tid * 8 + 4);                                 \
} while (0)

#define PUB_W(gg) do {                                                        \
    float* wd = &Wl[(gg) & 1][lr * WROW + lq * 8];                            \
    *(float4*)wd = wr0; *(float4*)(wd + 4) = wr1;                             \
} while (0)

#define LOAD_EA(ER, gg) do {                                                  \
    const uint4* src = EA4 + ((size_t)(bq + (gg))) * 1024 + tid;              \
    _Pragma("unroll")                                                         \
    for (int j = 0; j < 8; ++j) ER[j] = src[j * 128];                         \
} while (0)

// prefetch w row `rowidx` (compile-time after unroll) into 8 named float4s
#define PREF8(A0,A1,A2,A3,A4,A5,A6,A7, rowidx) do {                           \
    const float* _wr = wlc + (rowidx) * WROW;                                 \
    A0 = *(const float4*)(_wr + 0);  A1 = *(const float4*)(_wr + 4);          \
    A2 = *(const float4*)(_wr + 8);  A3 = *(const float4*)(_wr + 12);         \
    A4 = *(const float4*)(_wr + 16); A5 = *(const float4*)(_wr + 20);         \
    A6 = *(const float4*)(_wr + 24); A7 = *(const float4*)(_wr + 28);         \
} while (0)

// one chain step from 8 named register-resident float4s
#define STEP8(A0,A1,A2,A3,A4,A5,A6,A7, ER, tl) do {                           \
    f32x2 w2[16];                                                             \
    w2[0]  = mk2(A0.x, A0.y); w2[1]  = mk2(A0.z, A0.w);                       \
    w2[2]  = mk2(A1.x, A1.y); w2[3]  = mk2(A1.z, A1.w);                       \
    w2[4]  = mk2(A2.x, A2.y); w2[5]  = mk2(A2.z, A2.w);                       \
    w2[6]  = mk2(A3.x, A3.y); w2[7]  = mk2(A3.z, A3.w);                       \
    w2[8]  = mk2(A4.x, A4.y); w2[9]  = mk2(A4.z, A4.w);                       \
    w2[10] = mk2(A5.x, A5.y); w2[11] = mk2(A5.z, A5.w);                       \
    w2[12] = mk2(A6.x, A6.y); w2[13] = mk2(A6.z, A6.w);                       \
    w2[14] = mk2(A7.x, A7.y); w2[15] = mk2(A7.z, A7.w);                       \
    unsigned ea = u4get(ER[(tl) >> 2], (tl) & 3);                             \
    float e = __uint_as_float(ea << 16);                                      \
    float a = __uint_as_float(ea & 0xffff0000u);                              \
    f32x2 ne2 = mk2(-e, -e);                                                  \
    f32x2 a2  = mk2(a, a);                                                    \
    f32x2 r0 = mk2(0.f, 0.f), r1 = r0, r2 = r0, r3 = r0;                      \
    _Pragma("unroll")                                                         \
    for (int q = 0; q < 4; ++q) {                                             \
        r0 = fma2(w2[4*q+0], Mv2[4*q+0], r0);                                 \
        r1 = fma2(w2[4*q+1], Mv2[4*q+1], r1);                                 \
        r2 = fma2(w2[4*q+2], Mv2[4*q+2], r2);                                 \
        r3 = fma2(w2[4*q+3], Mv2[4*q+3], r3);                                 \
    }                                                                         \
    f32x2 rs = (r0 + r1) + (r2 + r3);                                         \
    slp[(tl) * RSTR + tid] = f2bf(rs.x + rs.y);                               \
    _Pragma("unroll")                                                         \
    for (int i = 0; i < 16; ++i)                                              \
        Mv2[i] = fma2(w2[i], fma2(ne2, Mv2[i], a2), Mv2[i]);                  \
} while (0)

// chunk with sched_barrier-pinned DISTANCE-2 w pipeline (4 buffer sets)
#define SEQ_CHUNK(ER, gg, SL) do {                                            \
    const float* wlc = Wl[(gg) & 1];                                          \
    unsigned short* slp = SL;                                                 \
    PREF8(w0,w1,w2_,w3_,w4_,w5_,w6_,w7_, 0);                                  \
    PREF8(u0,u1,u2,u3,u4,u5,u6,u7, 1);                                        \
    _Pragma("unroll")                                                         \
    for (int tp = 0; tp < 8; ++tp) {                                          \
        SB(); PREF8(v0,v1,v2,v3,v4,v5,v6,v7, 4 * tp + 2); SB();               \
        STEP8(w0,w1,w2_,w3_,w4_,w5_,w6_,w7_, ER, 4 * tp);                     \
        SB(); PREF8(x0,x1,x2,x3,x4,x5,x6,x7, 4 * tp + 3); SB();               \
        STEP8(u0,u1,u2,u3,u4,u5,u6,u7, ER, 4 * tp + 1);                       \
        SB(); PREF8(w0,w1,w2_,w3_,w4_,w5_,w6_,w7_,                            \
                    (4 * tp + 4 < 32) ? (4 * tp + 4) : 31); SB();             \
        STEP8(v0,v1,v2,v3,v4,v5,v6,v7, ER, 4 * tp + 2);                       \
        SB(); PREF8(u0,u1,u2,u3,u4,u5,u6,u7,                                  \
                    (4 * tp + 5 < 32) ? (4 * tp + 5) : 31); SB();             \
        STEP8(x0,x1,x2,x3,x4,x5,x6,x7, ER, 4 * tp + 3);                       \
    }                                                                         \
} while (0)

__device__ __forceinline__ void consume_chunk(
    int gc, const unsigned short* sl, const unsigned short* fWl,
    int b, int Tc, int t0,
    const unsigned short* __restrict__ Ko, const float* __restrict__ pW,
    float pbv, float* __restrict__ pred, int tid)
{
    const int lane = tid & 63;
    const int cw = (tid >> 6) & 1;          // consumer wave 0/1 -> rows cw*16..+15
    const int mrow = lane & 15, quad = lane >> 4;
    s16x8 aF[4];
#pragma unroll
    for (int kb = 0; kb < 4; ++kb)
        aF[kb] = *(const s16x8*)&sl[(cw * 16 + mrow) * RSTR + kb * 32 + quad * 8];
    float p0 = 0.f, p1 = 0.f, p2 = 0.f, p3 = 0.f;
    size_t rbase = (size_t)b * Tc + gc * CH + cw * 16 + quad * 4;
#pragma unroll
    for (int nt = 0; nt < 8; ++nt) {
        f32x4 acc = {0.f, 0.f, 0.f, 0.f};
#pragma unroll
        for (int kb = 0; kb < 4; ++kb) {
            s16x8 bf = *(const s16x8*)&fWl[(nt * 16 + mrow) * RSTR + kb * 32 + quad * 8];
            acc = __builtin_amdgcn_mfma_f32_16x16x32_bf16(aF[kb], bf, acc, 0, 0, 0);
        }
        int col = nt * 16 + mrow;
        float pw = pW[col];
        p0 = fmaf(fast_tanh(acc[0] + bf2f(Ko[(rbase + 0) * 128 + col])), pw, p0);
        p1 = fmaf(fast_tanh(acc[1] + bf2f(Ko[(rbase + 1) * 128 + col])), pw, p1);
        p2 = fmaf(fast_tanh(acc[2] + bf2f(Ko[(rbase + 2) * 128 + col])), pw, p2);
        p3 = fmaf(fast_tanh(acc[3] + bf2f(Ko[(rbase + 3) * 128 + col])), pw, p3);
    }
#pragma unroll
    for (int off = 1; off < 16; off <<= 1) {
        p0 += __shfl_xor(p0, off, 64); p1 += __shfl_xor(p1, off, 64);
        p2 += __shfl_xor(p2, off, 64); p3 += __shfl_xor(p3, off, 64);
    }
    if (mrow == 0) {
        int tb = t0 + gc * CH + cw * 16 + quad * 4;
        float ps[4] = {p0, p1, p2, p3};
#pragma unroll
        for (int reg = 0; reg < 4; ++reg) {
            int t = tb + reg;
            if (t < TT - 1) pred[b * (TT - 1) + t] = fast_sigmoid(ps[reg] + pbv);
        }
    }
}

__global__ __launch_bounds__(256, 1) void fused_kernel(
    const float* __restrict__ W, const unsigned* __restrict__ EA,
    const float* __restrict__ Mv0, const unsigned short* __restrict__ Ko,
    const unsigned short* __restrict__ fWat, const float* __restrict__ pW,
    const float* __restrict__ pb,
    float* __restrict__ pred, float* __restrict__ MvWS,
    int t0, int Tc, int doInit, int doSave)
{
    const int b = blockIdx.x;
    const int tid = threadIdx.x;
    const int nch = Tc / CH;

    __shared__ __align__(16) float Wl[2][CH * WROW];            //  9.2 KB
    __shared__ __align__(16) unsigned short rtl[2][CH * RSTR];  // 17.4 KB
    __shared__ __align__(16) unsigned short fWl[128 * RSTR];    // 34.8 KB

    // stage fWat -> fWl (all 256 threads)
    {
        int n = tid >> 1, k0 = (tid & 1) * 64;
#pragma unroll
        for (int j = 0; j < 8; ++j)
            *(s16x8*)&fWl[n * RSTR + k0 + j * 8] = *(const s16x8*)&fWat[n * 128 + k0 + j * 8];
    }

    const int lr = tid >> 2, lq = tid & 3;
    const float* __restrict__ Wb = W + (size_t)b * Tc * 32;
    const uint4* __restrict__ EA4 = (const uint4*)EA;
    const int bq = b * nch;
    f32x2 Mv2[16];
    float4 wr0, wr1;
    float4 w0, w1, w2_, w3_, w4_, w5_, w6_, w7_;
    float4 u0, u1, u2, u3, u4, u5, u6, u7;
    float4 v0, v1, v2, v3, v4, v5, v6, v7;
    float4 x0, x1, x2, x3, x4, x5, x6, x7;
    uint4 erA[8], erB[8];
    float pbv = 0.f;

    if (tid < 128) {
        if (doInit) {
#pragma unroll
            for (int i = 0; i < 16; ++i)
                Mv2[i] = mk2(Mv0[(2 * i) * 128 + tid], Mv0[(2 * i + 1) * 128 + tid]);
        } else {
#pragma unroll
            for (int i = 0; i < 16; ++i)
                Mv2[i] = mk2(MvWS[(size_t)b * 4096 + (2 * i) * 128 + tid],
                             MvWS[(size_t)b * 4096 + (2 * i + 1) * 128 + tid]);
        }
        LOAD_W(0); PUB_W(0);
        LOAD_EA(erA, 0);
        if (nch > 1) LOAD_W(1);
    } else {
        pbv = pb[0];
    }
    __syncthreads();

    for (int g = 0; g < nch; g += 2) {
        // ---- even chunk g: produce -> slot0; consume chunk g-1 (slot1) ----
        if (tid < 128) {
            if (g + 1 < nch) PUB_W(g + 1);
            if (g + 2 < nch) LOAD_W(g + 2);
            if (g + 1 < nch) LOAD_EA(erB, g + 1);
            SEQ_CHUNK(erA, g, rtl[0]);
        } else if (g >= 1) {
            consume_chunk(g - 1, rtl[1], fWl, b, Tc, t0, Ko, pW, pbv, pred, tid);
        }
        __syncthreads();

        // ---- odd chunk g+1: produce -> slot1; consume chunk g (slot0) ----
        if (tid < 128) {
            if (g + 1 < nch) {
                if (g + 2 < nch) PUB_W(g + 2);
                if (g + 3 < nch) LOAD_W(g + 3);
                if (g + 2 < nch) LOAD_EA(erA, g + 2);
                SEQ_CHUNK(erB, g + 1, rtl[1]);
            }
        } else {
            consume_chunk(g, rtl[0], fWl, b, Tc, t0, Ko, pW, pbv, pred, tid);
        }
        __syncthreads();
    }
    // epilogue: for even nch the last (odd) chunk is still unconsumed
    if (!(nch & 1) && tid >= 128) {
        consume_chunk(nch - 1, rtl[1], fWl, b, Tc, t0, Ko, pW, pbv, pred, tid);
    }

    if (doSave && tid < 128) {
#pragma unroll
        for (int i = 0; i < 16; ++i) {
            MvWS[(size_t)b * 4096 + (2 * i) * 128 + tid]     = Mv2[i].x;
            MvWS[(size_t)b * 4096 + (2 * i + 1) * 128 + tid] = Mv2[i].y;
        }
    }
}

// ---------------------------------------------------------------------------

extern "C" void kernel_launch(void* const* d_in, const int* in_sizes, int n_in,
                              void* d_out, int out_size, void* d_ws, size_t ws_size,
                              hipStream_t stream) {
    const int*   skills    = (const int*)d_in[0];
    const int*   responses = (const int*)d_in[1];
    const float* k_emb     = (const float*)d_in[2];
    const float* v_emb     = (const float*)d_in[3];
    const float* Mk        = (const float*)d_in[4];
    const float* Mv0       = (const float*)d_in[5];
    const float* f_W       = (const float*)d_in[6];
    const float* f_b       = (const float*)d_in[7];
    const float* p_W       = (const float*)d_in[8];
    const float* p_b       = (const float*)d_in[9];
    const float* e_W       = (const float*)d_in[10];
    const float* e_b       = (const float*)d_in[11];
    const float* a_W       = (const float*)d_in[12];
    const float* a_b       = (const float*)d_in[13];

    float* pred    = (float*)d_out;                 // [256][255]
    float* outTrue = pred + BB * (TT - 1);          // [256][255]

    // scratch per row: Wo 128 B + EA 512 B + Ko 256 B = 896 B
    int Tc = TT;
    for (;;) {
        size_t need = (size_t)BB * Tc * 896 + 69632 * 2;
        if (Tc < TT) need += (size_t)BB * 4096 * 4;
        if (need <= ws_size || Tc <= 32) break;
        Tc >>= 1;
    }

    char* p = (char*)d_ws;
    float* Wo = (float*)p;                     p += (size_t)BB * Tc * 32 * 4;
    unsigned* EA = (unsigned*)p;               p += (size_t)BB * Tc * 128 * 4;
    unsigned short* Ko = (unsigned short*)p;   p += (size_t)BB * Tc * 128 * 2;
    unsigned short* eWt = (unsigned short*)p;  p += 16384 * 2;
    unsigned short* aWt = (unsigned short*)p;  p += 16384 * 2;
    unsigned short* fWat = (unsigned short*)p; p += 16384 * 2;
    unsigned short* fWbt = (unsigned short*)p; p += 16384 * 2;
    unsigned short* Mkt = (unsigned short*)p;  p += 4096 * 2;
    float* MvWS = (float*)p;

    conv_kernel<<<272, 256, 0, stream>>>(e_W, a_W, f_W, Mk,
                                         eWt, aWt, fWat, fWbt, Mkt);

    for (int t0 = 0; t0 < TT; t0 += Tc) {
        pre_kernel<<<(BB * Tc) / 64, 256, 0, stream>>>(
            skills, responses, k_emb, v_emb, f_b, e_b, a_b,
            Mkt, fWbt, eWt, aWt, Wo, EA, Ko, outTrue, t0, Tc);
        fused_kernel<<<BB, 256, 0, stream>>>(
            Wo, EA, Mv0, Ko, fWat, p_W, p_b, pred, MvWS,
            t0, Tc, t0 == 0 ? 1 : 0, (t0 + Tc < TT) ? 1 : 0);
    }
}

// Round 8
// 157.534 us; speedup vs baseline: 1.3317x; 1.0374x over previous
//
#include <hip/hip_runtime.h>
#include <math.h>

// Problem constants (fixed by setup_inputs)
#define BB 256      // batch
#define TT 256      // time steps
#define NQ 1000     // num_q
#define DK 128
#define DV 128
#define CC 32

typedef short s16x8 __attribute__((ext_vector_type(8)));   // 8 bf16 bit-patterns
typedef float f32x4 __attribute__((ext_vector_type(4)));
typedef float f32x2 __attribute__((ext_vector_type(2)));

__device__ __forceinline__ float fast_sigmoid(float x) {
    x = fminf(fmaxf(x, -30.f), 30.f);
    return 1.f / (1.f + __expf(-x));
}
__device__ __forceinline__ float fast_tanh(float x) {
    x = fminf(fmaxf(x, -15.f), 15.f);
    float t = __expf(2.f * x);
    return (t - 1.f) / (t + 1.f);
}
__device__ __forceinline__ unsigned short f2bf(float f) {   // RNE fp32->bf16
    unsigned u = __float_as_uint(f);
    u += 0x7fffu + ((u >> 16) & 1u);
    return (unsigned short)(u >> 16);
}
__device__ __forceinline__ float bf2f(unsigned short h) {
    return __uint_as_float((unsigned)h << 16);
}
__device__ __forceinline__ unsigned u4get(uint4 v, int i) { // i constant after unroll
    return i == 0 ? v.x : i == 1 ? v.y : i == 2 ? v.z : v.w;
}
__device__ __forceinline__ f32x2 mk2(float x, float y) { f32x2 r; r.x = x; r.y = y; return r; }
__device__ __forceinline__ f32x2 fma2(f32x2 a, f32x2 b, f32x2 c) {
    return __builtin_elementwise_fma(a, b, c);
}
__device__ __forceinline__ s16x8 cvt8(float4 v0, float4 v1) {
    s16x8 f;
    f[0] = (short)f2bf(v0.x); f[1] = (short)f2bf(v0.y);
    f[2] = (short)f2bf(v0.z); f[3] = (short)f2bf(v0.w);
    f[4] = (short)f2bf(v1.x); f[5] = (short)f2bf(v1.y);
    f[6] = (short)f2bf(v1.z); f[7] = (short)f2bf(v1.w);
    return f;
}

// ---------------------------------------------------------------------------
// conv_kernel: build bf16 TRANSPOSED weights in ws (B-operand layout Wt[n][k])
// ---------------------------------------------------------------------------
__global__ __launch_bounds__(256) void conv_kernel(
    const float* __restrict__ eW, const float* __restrict__ aW,
    const float* __restrict__ fW, const float* __restrict__ Mk,
    unsigned short* __restrict__ eWt, unsigned short* __restrict__ aWt,
    unsigned short* __restrict__ fWat, unsigned short* __restrict__ fWbt,
    unsigned short* __restrict__ Mkt)
{
    int idx = blockIdx.x * 256 + threadIdx.x;
    if (idx < 16384) {
        int n = idx >> 7, k = idx & 127;
        eWt[idx] = f2bf(eW[k * 128 + n]);
    } else if (idx < 32768) {
        int i = idx - 16384; int n = i >> 7, k = i & 127;
        aWt[i] = f2bf(aW[k * 128 + n]);
    } else if (idx < 49152) {
        int i = idx - 32768; int n = i >> 7, k = i & 127;
        fWat[i] = f2bf(fW[k * 128 + n]);
    } else if (idx < 65536) {
        int i = idx - 49152; int n = i >> 7, k = i & 127;
        fWbt[i] = f2bf(fW[(128 + k) * 128 + n]);
    } else if (idx < 69632) {
        int i = idx - 65536; int n = i >> 7, k = i & 127;   // n=c 0..31
        Mkt[i] = f2bf(Mk[k * 32 + n]);
    }
}

// ---------------------------------------------------------------------------
// pre_kernel v2 (R11): same math, data movement minimized.
// ---------------------------------------------------------------------------
__global__ __launch_bounds__(256) void pre_kernel(
    const int* __restrict__ skills, const int* __restrict__ responses,
    const float* __restrict__ k_emb, const float* __restrict__ v_emb,
    const float* __restrict__ fb, const float* __restrict__ eb,
    const float* __restrict__ ab,
    const unsigned short* __restrict__ Mkt, const unsigned short* __restrict__ fWbt,
    const unsigned short* __restrict__ eWt, const unsigned short* __restrict__ aWt,
    float* __restrict__ Wo, unsigned* __restrict__ EA,
    unsigned short* __restrict__ Ko, float* __restrict__ outTrue,
    int t0, int Tc)
{
    const int tid = threadIdx.x;
    const int lane = tid & 63;
    const int m_base = (tid >> 6) * 16;
    const int mrow = lane & 15, quad = lane >> 4;
    const size_t base = (size_t)blockIdx.x * 64;

    __shared__ __align__(16) unsigned short Wlds[128 * 136];   // 34.8 KB

    // per-lane gather row (A-side): row = base + m_base + mrow
    int grow = (int)base + m_base + mrow;
    int gb = grow / Tc;
    int gt = t0 + (grow - gb * Tc);
    int gi = gb * TT + gt;
    int s = skills[gi];
    int r = responses[gi];
    int q = s + NQ * ((r > -1) ? r : 0);
    if (quad == 0 && gt >= 1) outTrue[gb * (TT - 1) + (gt - 1)] = (float)r;

    // stage Mkt rows 0..31
    {
        int n = tid >> 3, k0 = (tid & 7) * 16;
        *(s16x8*)&Wlds[n * 136 + k0]     = *(const s16x8*)&Mkt[n * 128 + k0];
        *(s16x8*)&Wlds[n * 136 + k0 + 8] = *(const s16x8*)&Mkt[n * 128 + k0 + 8];
    }

    // gather kt A-frags direct to regs: aF[kb] = kt[row][kb*32 + quad*8 ..+7]
    s16x8 aF[4];
    {
        const float* kr = k_emb + (size_t)s * DK + quad * 8;
#pragma unroll
        for (int kb = 0; kb < 4; ++kb)
            aF[kb] = cvt8(*(const float4*)(kr + kb * 32),
                          *(const float4*)(kr + kb * 32 + 4));
    }
    __syncthreads();   // [1] Mkt staged

    // logits (NT=2) + in-register softmax -> Wo
    {
        f32x4 l0 = {0.f, 0.f, 0.f, 0.f}, l1 = {0.f, 0.f, 0.f, 0.f};
#pragma unroll
        for (int kb = 0; kb < 4; ++kb) {
            s16x8 b0 = *(const s16x8*)&Wlds[mrow * 136 + kb * 32 + quad * 8];
            s16x8 b1 = *(const s16x8*)&Wlds[(16 + mrow) * 136 + kb * 32 + quad * 8];
            l0 = __builtin_amdgcn_mfma_f32_16x16x32_bf16(aF[kb], b0, l0, 0, 0, 0);
            l1 = __builtin_amdgcn_mfma_f32_16x16x32_bf16(aF[kb], b1, l1, 0, 0, 0);
        }
        // lane holds cols {mrow, 16+mrow} for rows m_base + quad*4 + reg
#pragma unroll
        for (int reg = 0; reg < 4; ++reg) {
            float a0 = l0[reg], a1 = l1[reg];
            float m = fmaxf(a0, a1);
#pragma unroll
            for (int off = 1; off < 16; off <<= 1)
                m = fmaxf(m, __shfl_xor(m, off, 64));
            float e0 = __expf(a0 - m), e1 = __expf(a1 - m);
            float ssum = e0 + e1;
#pragma unroll
            for (int off = 1; off < 16; off <<= 1)
                ssum += __shfl_xor(ssum, off, 64);
            float inv = 1.f / ssum;
            size_t rowg = base + m_base + quad * 4 + reg;
            Wo[rowg * 32 + mrow]      = e0 * inv;
            Wo[rowg * 32 + 16 + mrow] = e1 * inv;
        }
    }
    __syncthreads();   // [2] logits' Wlds reads done

    // stage fWbt
    {
        int n = tid >> 1, k0 = (tid & 1) * 64;
#pragma unroll
        for (int j = 0; j < 8; ++j)
            *(s16x8*)&Wlds[n * 136 + k0 + j * 8] = *(const s16x8*)&fWbt[n * 128 + k0 + j * 8];
    }
    __syncthreads();   // [3]

    // gather vt frags early (global latency overlaps ck MFMA below)
    s16x8 vF[4];
    {
        const float* vr = v_emb + (size_t)q * DV + quad * 8;
#pragma unroll
        for (int kb = 0; kb < 4; ++kb)
            vF[kb] = cvt8(*(const float4*)(vr + kb * 32),
                          *(const float4*)(vr + kb * 32 + 4));
    }

    // ck = kt@fWb + fb -> Ko
#pragma unroll
    for (int nt = 0; nt < 8; ++nt) {
        f32x4 acc = {0.f, 0.f, 0.f, 0.f};
#pragma unroll
        for (int kb = 0; kb < 4; ++kb) {
            s16x8 bf = *(const s16x8*)&Wlds[(nt * 16 + mrow) * 136 + kb * 32 + quad * 8];
            acc = __builtin_amdgcn_mfma_f32_16x16x32_bf16(aF[kb], bf, acc, 0, 0, 0);
        }
        int col = nt * 16 + mrow;
        float fbv = fb[col];
#pragma unroll
        for (int reg = 0; reg < 4; ++reg) {
            size_t rr = base + m_base + quad * 4 + reg;
            Ko[rr * 128 + col] = f2bf(acc[reg] + fbv);
        }
    }
    __syncthreads();   // [4] ck's Wlds reads done

    // stage eWt
    {
        int n = tid >> 1, k0 = (tid & 1) * 64;
#pragma unroll
        for (int j = 0; j < 8; ++j)
            *(s16x8*)&Wlds[n * 136 + k0 + j * 8] = *(const s16x8*)&eWt[n * 128 + k0 + j * 8];
    }
    __syncthreads();   // [5]

    // et = sigmoid(vt@eW + eb) -> registers
    float etr[8][4];
#pragma unroll
    for (int nt = 0; nt < 8; ++nt) {
        f32x4 acc = {0.f, 0.f, 0.f, 0.f};
#pragma unroll
        for (int kb = 0; kb < 4; ++kb) {
            s16x8 bf = *(const s16x8*)&Wlds[(nt * 16 + mrow) * 136 + kb * 32 + quad * 8];
            acc = __builtin_amdgcn_mfma_f32_16x16x32_bf16(vF[kb], bf, acc, 0, 0, 0);
        }
        int col = nt * 16 + mrow;
        float ebv = eb[col];
#pragma unroll
        for (int reg = 0; reg < 4; ++reg)
            etr[nt][reg] = fast_sigmoid(acc[reg] + ebv);
    }
    __syncthreads();   // [6] et's Wlds reads done

    // stage aWt
    {
        int n = tid >> 1, k0 = (tid & 1) * 64;
#pragma unroll
        for (int j = 0; j < 8; ++j)
            *(s16x8*)&Wlds[n * 136 + k0 + j * 8] = *(const s16x8*)&aWt[n * 128 + k0 + j * 8];
    }
    __syncthreads();   // [7]

    // at = tanh(vt@aW + ab); pack (et,at) -> EA
#pragma unroll
    for (int nt = 0; nt < 8; ++nt) {
        f32x4 acc = {0.f, 0.f, 0.f, 0.f};
#pragma unroll
        for (int kb = 0; kb < 4; ++kb) {
            s16x8 bf = *(const s16x8*)&Wlds[(nt * 16 + mrow) * 136 + kb * 32 + quad * 8];
            acc = __builtin_amdgcn_mfma_f32_16x16x32_bf16(vF[kb], bf, acc, 0, 0, 0);
        }
        int col = nt * 16 + mrow;
        float abv = ab[col];
#pragma unroll
        for (int reg = 0; reg < 4; ++reg) {
            size_t rr = base + m_base + quad * 4 + reg;
            int bb = (int)(rr / (size_t)Tc);
            int t  = (int)(rr - (size_t)bb * Tc);
            size_t o4 = (((size_t)bb * (Tc >> 5) + (t >> 5)) * 8 + ((t >> 2) & 7)) * 128 + col;
            unsigned lo = f2bf(etr[nt][reg]);
            unsigned hi = (unsigned)f2bf(fast_tanh(acc[reg] + abv)) << 16;
            EA[o4 * 4 + (t & 3)] = hi | lo;
        }
    }
}

// ---------------------------------------------------------------------------
// fused_kernel v12 (seq + post) — R18:
//  512-thread ROLE-SPLIT redesign on the proven R1/R7 chunk rhythm.
//  Roles by tid>>7: 0/1 = producer wave-pairs (c-half ch*16..+15, d=tid&127),
//  2 = consumers (unchanged consume, reads summed partials), 3 = stagers
//  (all W->Wl staging). Per-producer-wave issue HALVES (R6's split, but
//  consume stays concurrent on dedicated waves — R6's failure mode removed);
//  2 waves/SIMD co-residency (8 waves/CU OK to 256 VGPR per m69) hides the
//  ~40% per-wave stall R7 couldn't. Dot partials stored f32 to two LDS
//  arrays (stride 132 f32: step writes conflict-free + 16B-aligned reads);
//  consumer sums f32 then rounds ONCE to bf16 (same reassoc R6 validated,
//  absmax unchanged). LDS 61.4 -> 109 KB (<=160 KB; grid=256 -> 1 block/CU
//  regardless).
// ---------------------------------------------------------------------------

#define CH 32
#define WROW 36     // Wl row stride (floats)
#define RSTR 136    // fWl row stride (shorts)
#define PSTR 132    // rt partial row stride (floats): 16B-aligned, step-write conflict-free
#define SB() __builtin_amdgcn_sched_barrier(0)

#define LOAD_W(gg) do {                                                       \
    const float* ws = Wb + (size_t)(gg) * CH * 32;                            \
    wr0 = *(const float4*)(ws + dd * 8);                                      \
    wr1 = *(const float4*)(ws + dd * 8 + 4);                                  \
} while (0)

#define PUB_W(gg) do {                                                        \
    float* wd = &Wl[(gg) & 1][lr * WROW + lq * 8];                            \
    *(float4*)wd = wr0; *(float4*)(wd + 4) = wr1;                             \
} while (0)

#define LOAD_EA(ER, gg) do {                                                  \
    const uint4* src = EA4 + ((size_t)(bq + (gg))) * 1024 + dd;               \
    _Pragma("unroll")                                                         \
    for (int j = 0; j < 8; ++j) ER[j] = src[j * 128];                         \
} while (0)

// prefetch this producer's 16 w floats of row `rowidx` into 4 named float4s
#define PREF4(A0,A1,A2,A3, rowidx) do {                                       \
    const float* _wr = wlc + (rowidx) * WROW;                                 \
    A0 = *(const float4*)(_wr + 0);  A1 = *(const float4*)(_wr + 4);          \
    A2 = *(const float4*)(_wr + 8);  A3 = *(const float4*)(_wr + 12);         \
} while (0)

// one chain step on this producer's 16-c half; f32 partial -> own LDS array
#define STEP4(A0,A1,A2,A3, ER, tl) do {                                       \
    f32x2 w2[8];                                                              \
    w2[0] = mk2(A0.x, A0.y); w2[1] = mk2(A0.z, A0.w);                         \
    w2[2] = mk2(A1.x, A1.y); w2[3] = mk2(A1.z, A1.w);                         \
    w2[4] = mk2(A2.x, A2.y); w2[5] = mk2(A2.z, A2.w);                         \
    w2[6] = mk2(A3.x, A3.y); w2[7] = mk2(A3.z, A3.w);                         \
    unsigned ea = u4get(ER[(tl) >> 2], (tl) & 3);                             \
    float e  = __uint_as_float(ea << 16);                                     \
    float av = __uint_as_float(ea & 0xffff0000u);                             \
    f32x2 ne2 = mk2(-e, -e);                                                  \
    f32x2 a2  = mk2(av, av);                                                  \
    f32x2 r0 = mk2(0.f, 0.f), r1 = r0, r2 = r0, r3 = r0;                      \
    r0 = fma2(w2[0], Mv2[0], r0); r1 = fma2(w2[1], Mv2[1], r1);               \
    r2 = fma2(w2[2], Mv2[2], r2); r3 = fma2(w2[3], Mv2[3], r3);               \
    r0 = fma2(w2[4], Mv2[4], r0); r1 = fma2(w2[5], Mv2[5], r1);               \
    r2 = fma2(w2[6], Mv2[6], r2); r3 = fma2(w2[7], Mv2[7], r3);               \
    f32x2 rs = (r0 + r1) + (r2 + r3);                                         \
    slp[(tl) * PSTR + dd] = rs.x + rs.y;                                      \
    _Pragma("unroll")                                                         \
    for (int i = 0; i < 8; ++i)                                               \
        Mv2[i] = fma2(w2[i], fma2(ne2, Mv2[i], a2), Mv2[i]);                  \
} while (0)

// chunk with sched_barrier-pinned distance-2 w pipeline (4 buffer sets)
#define SEQ_CHUNK4(ER, gg) do {                                               \
    const float* wlc = Wl[(gg) & 1] + ch16;                                   \
    float* slp = ch ? &rt1[(gg) & 1][0] : &rt0[(gg) & 1][0];                  \
    PREF4(w0, w1, w2_, w3_, 0);                                               \
    PREF4(u0, u1, u2, u3, 1);                                                 \
    _Pragma("unroll")                                                         \
    for (int tp = 0; tp < 8; ++tp) {                                          \
        SB(); PREF4(v0, v1, v2, v3, 4 * tp + 2); SB();                        \
        STEP4(w0, w1, w2_, w3_, ER, 4 * tp);                                  \
        SB(); PREF4(x0, x1, x2, x3, 4 * tp + 3); SB();                        \
        STEP4(u0, u1, u2, u3, ER, 4 * tp + 1);                                \
        SB(); PREF4(w0, w1, w2_, w3_,                                         \
                    (4 * tp + 4 < 32) ? (4 * tp + 4) : 31); SB();             \
        STEP4(v0, v1, v2, v3, ER, 4 * tp + 2);                                \
        SB(); PREF4(u0, u1, u2, u3,                                           \
                    (4 * tp + 5 < 32) ? (4 * tp + 5) : 31); SB();             \
        STEP4(x0, x1, x2, x3, ER, 4 * tp + 3);                                \
    }                                                                         \
} while (0)

__device__ __forceinline__ void consume_chunk(
    int gc, const float* r0p, const float* r1p, const unsigned short* fWl,
    int b, int Tc, int t0,
    const unsigned short* __restrict__ Ko, const float* __restrict__ pW,
    float pbv, float* __restrict__ pred, int tid)
{
    const int lane = tid & 63;
    const int cw = (tid >> 6) & 1;          // consumer wave 0/1 -> rows cw*16..+15
    const int mrow = lane & 15, quad = lane >> 4;
    s16x8 aF[4];
#pragma unroll
    for (int kb = 0; kb < 4; ++kb) {
        const float* s0 = r0p + (cw * 16 + mrow) * PSTR + kb * 32 + quad * 8;
        const float* s1 = r1p + (cw * 16 + mrow) * PSTR + kb * 32 + quad * 8;
        float4 xa = *(const float4*)s0, xb = *(const float4*)(s0 + 4);
        float4 ya = *(const float4*)s1, yb = *(const float4*)(s1 + 4);
        float4 sa, sb;
        sa.x = xa.x + ya.x; sa.y = xa.y + ya.y; sa.z = xa.z + ya.z; sa.w = xa.w + ya.w;
        sb.x = xb.x + yb.x; sb.y = xb.y + yb.y; sb.z = xb.z + yb.z; sb.w = xb.w + yb.w;
        aF[kb] = cvt8(sa, sb);
    }
    float p0 = 0.f, p1 = 0.f, p2 = 0.f, p3 = 0.f;
    size_t rbase = (size_t)b * Tc + gc * CH + cw * 16 + quad * 4;
#pragma unroll
    for (int nt = 0; nt < 8; ++nt) {
        f32x4 acc = {0.f, 0.f, 0.f, 0.f};
#pragma unroll
        for (int kb = 0; kb < 4; ++kb) {
            s16x8 bf = *(const s16x8*)&fWl[(nt * 16 + mrow) * RSTR + kb * 32 + quad * 8];
            acc = __builtin_amdgcn_mfma_f32_16x16x32_bf16(aF[kb], bf, acc, 0, 0, 0);
        }
        int col = nt * 16 + mrow;
        float pw = pW[col];
        p0 = fmaf(fast_tanh(acc[0] + bf2f(Ko[(rbase + 0) * 128 + col])), pw, p0);
        p1 = fmaf(fast_tanh(acc[1] + bf2f(Ko[(rbase + 1) * 128 + col])), pw, p1);
        p2 = fmaf(fast_tanh(acc[2] + bf2f(Ko[(rbase + 2) * 128 + col])), pw, p2);
        p3 = fmaf(fast_tanh(acc[3] + bf2f(Ko[(rbase + 3) * 128 + col])), pw, p3);
    }
#pragma unroll
    for (int off = 1; off < 16; off <<= 1) {
        p0 += __shfl_xor(p0, off, 64); p1 += __shfl_xor(p1, off, 64);
        p2 += __shfl_xor(p2, off, 64); p3 += __shfl_xor(p3, off, 64);
    }
    if (mrow == 0) {
        int tb = t0 + gc * CH + cw * 16 + quad * 4;
        float ps[4] = {p0, p1, p2, p3};
#pragma unroll
        for (int reg = 0; reg < 4; ++reg) {
            int t = tb + reg;
            if (t < TT - 1) pred[b * (TT - 1) + t] = fast_sigmoid(ps[reg] + pbv);
        }
    }
}

__global__ __launch_bounds__(512, 1) void fused_kernel(
    const float* __restrict__ W, const unsigned* __restrict__ EA,
    const float* __restrict__ Mv0, const unsigned short* __restrict__ Ko,
    const unsigned short* __restrict__ fWat, const float* __restrict__ pW,
    const float* __restrict__ pb,
    float* __restrict__ pred, float* __restrict__ MvWS,
    int t0, int Tc, int doInit, int doSave)
{
    const int b = blockIdx.x;
    const int tid = threadIdx.x;
    const int nch = Tc / CH;
    const int role = tid >> 7;      // 0/1: producers, 2: consumers, 3: stagers
    const int dd = tid & 127;
    const int ch = role & 1;        // producer c-half (valid for role<2)
    const int ch16 = ch * 16;

    __shared__ __align__(16) float Wl[2][CH * WROW];            //  9.2 KB
    __shared__ __align__(16) float rt0[2][CH * PSTR];           // 33.8 KB
    __shared__ __align__(16) float rt1[2][CH * PSTR];           // 33.8 KB
    __shared__ __align__(16) unsigned short fWl[128 * RSTR];    // 34.8 KB

    // stage fWat -> fWl (all 512 threads)
    {
        int n = tid >> 2, k0 = (tid & 3) * 32;
#pragma unroll
        for (int j = 0; j < 4; ++j)
            *(s16x8*)&fWl[n * RSTR + k0 + j * 8] = *(const s16x8*)&fWat[n * 128 + k0 + j * 8];
    }

    const int lr = dd >> 2, lq = tid & 3;
    const float* __restrict__ Wb = W + (size_t)b * Tc * 32;
    const uint4* __restrict__ EA4 = (const uint4*)EA;
    const int bq = b * nch;
    f32x2 Mv2[8];
    float4 wr0, wr1;
    float4 w0, w1, w2_, w3_;
    float4 u0, u1, u2, u3;
    float4 v0, v1, v2, v3;
    float4 x0, x1, x2, x3;
    uint4 erA[8], erB[8];
    float pbv = 0.f;

    if (role < 2) {
        if (doInit) {
#pragma unroll
            for (int i = 0; i < 8; ++i)
                Mv2[i] = mk2(Mv0[(ch16 + 2 * i) * 128 + dd],
                             Mv0[(ch16 + 2 * i + 1) * 128 + dd]);
        } else {
#pragma unroll
            for (int i = 0; i < 8; ++i)
                Mv2[i] = mk2(MvWS[(size_t)b * 4096 + (ch16 + 2 * i) * 128 + dd],
                             MvWS[(size_t)b * 4096 + (ch16 + 2 * i + 1) * 128 + dd]);
        }
        LOAD_EA(erA, 0);
    } else if (role == 3) {
        LOAD_W(0); PUB_W(0);
        if (nch > 1) LOAD_W(1);
    } else {
        pbv = pb[0];
    }
    __syncthreads();

    for (int g = 0; g < nch; g += 2) {
        // ---- even chunk g: produce -> slot0; consume g-1 (slot1); stage g+1/g+2 ----
        if (role < 2) {
            if (g + 1 < nch) LOAD_EA(erB, g + 1);
            SEQ_CHUNK4(erA, g);
        } else if (role == 2) {
            if (g >= 1)
                consume_chunk(g - 1, &rt0[(g - 1) & 1][0], &rt1[(g - 1) & 1][0],
                              fWl, b, Tc, t0, Ko, pW, pbv, pred, tid);
        } else {
            if (g + 1 < nch) PUB_W(g + 1);
            if (g + 2 < nch) LOAD_W(g + 2);
        }
        __syncthreads();

        // ---- odd chunk g+1: produce -> slot1; consume g (slot0); stage g+2/g+3 ----
        if (role < 2) {
            if (g + 1 < nch) {
                if (g + 2 < nch) LOAD_EA(erA, g + 2);
                SEQ_CHUNK4(erB, g + 1);
            }
        } else if (role == 2) {
            consume_chunk(g, &rt0[g & 1][0], &rt1[g & 1][0],
                          fWl, b, Tc, t0, Ko, pW, pbv, pred, tid);
        } else {
            if (g + 2 < nch) PUB_W(g + 2);
            if (g + 3 < nch) LOAD_W(g + 3);
        }
        __syncthreads();
    }
    // epilogue: for even nch the last (odd) chunk is still unconsumed
    if (!(nch & 1) && role == 2) {
        consume_chunk(nch - 1, &rt0[(nch - 1) & 1][0], &rt1[(nch - 1) & 1][0],
                      fWl, b, Tc, t0, Ko, pW, pbv, pred, tid);
    }

    if (doSave && role < 2) {
#pragma unroll
        for (int i = 0; i < 8; ++i) {
            MvWS[(size_t)b * 4096 + (ch16 + 2 * i) * 128 + dd]     = Mv2[i].x;
            MvWS[(size_t)b * 4096 + (ch16 + 2 * i + 1) * 128 + dd] = Mv2[i].y;
        }
    }
}

// ---------------------------------------------------------------------------

extern "C" void kernel_launch(void* const* d_in, const int* in_sizes, int n_in,
                              void* d_out, int out_size, void* d_ws, size_t ws_size,
                              hipStream_t stream) {
    const int*   skills    = (const int*)d_in[0];
    const int*   responses = (const int*)d_in[1];
    const float* k_emb     = (const float*)d_in[2];
    const float* v_emb     = (const float*)d_in[3];
    const float* Mk        = (const float*)d_in[4];
    const float* Mv0       = (const float*)d_in[5];
    const float* f_W       = (const float*)d_in[6];
    const float* f_b       = (const float*)d_in[7];
    const float* p_W       = (const float*)d_in[8];
    const float* p_b       = (const float*)d_in[9];
    const float* e_W       = (const float*)d_in[10];
    const float* e_b       = (const float*)d_in[11];
    const float* a_W       = (const float*)d_in[12];
    const float* a_b       = (const float*)d_in[13];

    float* pred    = (float*)d_out;                 // [256][255]
    float* outTrue = pred + BB * (TT - 1);          // [256][255]

    // scratch per row: Wo 128 B + EA 512 B + Ko 256 B = 896 B
    int Tc = TT;
    for (;;) {
        size_t need = (size_t)BB * Tc * 896 + 69632 * 2;
        if (Tc < TT) need += (size_t)BB * 4096 * 4;
        if (need <= ws_size || Tc <= 32) break;
        Tc >>= 1;
    }

    char* p = (char*)d_ws;
    float* Wo = (float*)p;                     p += (size_t)BB * Tc * 32 * 4;
    unsigned* EA = (unsigned*)p;               p += (size_t)BB * Tc * 128 * 4;
    unsigned short* Ko = (unsigned short*)p;   p += (size_t)BB * Tc * 128 * 2;
    unsigned short* eWt = (unsigned short*)p;  p += 16384 * 2;
    unsigned short* aWt = (unsigned short*)p;  p += 16384 * 2;
    unsigned short* fWat = (unsigned short*)p; p += 16384 * 2;
    unsigned short* fWbt = (unsigned short*)p; p += 16384 * 2;
    unsigned short* Mkt = (unsigned short*)p;  p += 4096 * 2;
    float* MvWS = (float*)p;

    conv_kernel<<<272, 256, 0, stream>>>(e_W, a_W, f_W, Mk,
                                         eWt, aWt, fWat, fWbt, Mkt);

    for (int t0 = 0; t0 < TT; t0 += Tc) {
        pre_kernel<<<(BB * Tc) / 64, 256, 0, stream>>>(
            skills, responses, k_emb, v_emb, f_b, e_b, a_b,
            Mkt, fWbt, eWt, aWt, Wo, EA, Ko, outTrue, t0, Tc);
        fused_kernel<<<BB, 512, 0, stream>>>(
            Wo, EA, Mv0, Ko, fWat, p_W, p_b, pred, MvWS,
            t0, Tc, t0 == 0 ? 1 : 0, (t0 + Tc < TT) ? 1 : 0);
    }
}